// Round 9
// baseline (251.930 us; speedup 1.0000x reference)
//
#include <hip/hip_runtime.h>
#include <hip/hip_bf16.h>
#include <math.h>

#define FEATN 12544
#define NIMG 1024

typedef __attribute__((ext_vector_type(8))) short short8;
typedef __attribute__((ext_vector_type(4))) float f32x4;

// ---- ws byte offsets (all sizes in BYTES; bf16 regions are 2 B/elem) ----
#define OFF_W1F   0            //  2048 bf16  =     4096 B   conv1 B-frag table
#define OFF_W2F   6144         //  32768 bf16 =    65536 B   conv2 B-frag table
#define OFF_WBBF  71680        //  1605632 bf16 = 3211264 B  gemm_u B-frag table
#define OFF_H1B   3282944      //  1024*28800 bf16 = 58982400 B
#define OFF_FEATB 62265344     //  1024*12544 bf16 = 25690112 B
#define OFF_U     87955456     //  131072 f32 = 524288 B   (layout [bg][t][c][q])
#define OFF_PART  88479744     //  28*131072 f32 = 14680064 B
#define OFF_HID   103159808    //  1024 f32 = 4096 B (unused now)
#define OFF_WHF   103163904    //  8192 bf16 = 16384 B   rnn Wh B-frag table
#define OFF_WGF   103180288    //  32768 bf16 = 65536 B  rnn [ff1|ff2|ta|tb] B-frag table
#define WS_BYTES  103245824

__device__ __forceinline__ unsigned short f2bf(float v) {
    union { float f; unsigned int u; } c; c.f = v;
    unsigned int r = c.u + 0x7FFFu + ((c.u >> 16) & 1u);   // RNE
    return (unsigned short)(r >> 16);
}
__device__ __forceinline__ float bf2f(unsigned short h) {
    union { unsigned int u; float f; } c; c.u = ((unsigned int)h) << 16;
    return c.f;
}

__device__ __forceinline__ float fast_tanh(float x) {
    x = fminf(fmaxf(x, -15.f), 15.f);
    float e = __expf(2.f * x);
    return (e - 1.f) * __builtin_amdgcn_rcpf(e + 1.f);
}
__device__ __forceinline__ float fast_sigmoid(float x) {
    x = fminf(fmaxf(x, -30.f), 30.f);
    return __builtin_amdgcn_rcpf(1.f + __expf(-x));
}

// unpack 8 packed dwords {lo16<<16|hi16} -> hi-frag, lo-frag (short8)  [HW-verified R8]
__device__ __forceinline__ void unpack8(uint4 a, uint4 b, short8* hi, short8* lo) {
    union { unsigned int u[4]; short8 s; } H, L;
    H.u[0] = __builtin_amdgcn_perm(a.y, a.x, 0x05040100u);
    H.u[1] = __builtin_amdgcn_perm(a.w, a.z, 0x05040100u);
    H.u[2] = __builtin_amdgcn_perm(b.y, b.x, 0x05040100u);
    H.u[3] = __builtin_amdgcn_perm(b.w, b.z, 0x05040100u);
    L.u[0] = __builtin_amdgcn_perm(a.y, a.x, 0x07060302u);
    L.u[1] = __builtin_amdgcn_perm(a.w, a.z, 0x07060302u);
    L.u[2] = __builtin_amdgcn_perm(b.y, b.x, 0x07060302u);
    L.u[3] = __builtin_amdgcn_perm(b.w, b.z, 0x07060302u);
    *hi = H.s; *lo = L.s;
}

// ---------------- merged weight-prep kernel (5-in-1) ----------------
__global__ __launch_bounds__(256) void prep_all(const float* __restrict__ w1, const float* __restrict__ w2,
                         const float* __restrict__ Wbb,
                         const float* __restrict__ Wff1, const float* __restrict__ Wff2,
                         const float* __restrict__ Wta,  const float* __restrict__ Wtb,
                         unsigned short* __restrict__ w1f, unsigned short* __restrict__ w2f,
                         unsigned short* __restrict__ wbbf,
                         unsigned short* __restrict__ whf, unsigned short* __restrict__ wgf) {
    int bid = blockIdx.x, tid = threadIdx.x;
    if (bid < 6272) {                       // Wbb(feat) -> wbbf, 1605632
        int i = bid * 256 + tid;
        int j = i & 7, lane = (i >> 3) & 63, nt = (i >> 9) & 7, kstep = i >> 12;
        int f = kstep * 32 + (lane >> 4) * 8 + j;
        int col = nt * 16 + (lane & 15);
        wbbf[i] = f2bf(Wbb[(size_t)f * 128 + col]);
    } else if (bid < 6400) {                // w2 -> w2f, 32768
        int i = (bid - 6272) * 256 + tid;
        int j = i & 7, lane = (i >> 3) & 63, kstep = (i >> 9) & 15, nt = i >> 13;
        int oc = nt * 16 + (lane & 15);
        int ic = 2 * kstep + (j >> 2);
        int ky = lane >> 4, kx = j & 3;
        w2f[i] = f2bf(w2[oc * 512 + ic * 16 + ky * 4 + kx]);
    } else if (bid < 6528) {                // gates -> wgf, 32768
        int i = (bid - 6400) * 256 + tid;
        int j = i & 7, lane = (i >> 3) & 63, nt = (i >> 9) & 15, kstep = (i >> 13) & 3;
        int k = kstep * 32 + ((lane >> 4) & 3) * 8 + j;
        int m = nt >> 2;
        int c = (nt & 3) * 16 + (lane & 15);
        const float* Wm = (m == 0) ? Wff1 : (m == 1) ? Wff2 : (m == 2) ? Wta : Wtb;
        wgf[i] = f2bf(Wm[k * 64 + c]);
    } else if (bid < 6560) {                // Wh -> whf, 8192
        int i = (bid - 6528) * 256 + tid;
        int j = i & 7, lane = (i >> 3) & 63, nt = (i >> 9) & 7, kstep = (i >> 12) & 1;
        int k = kstep * 32 + ((lane >> 4) & 3) * 8 + j;
        int col = nt * 16 + (lane & 15);
        whf[i] = f2bf(Wbb[(size_t)(FEATN + k) * 128 + col]);
    } else {                                // w1 -> w1f, 2048
        int i = (bid - 6560) * 256 + tid;
        if (i >= 2048) return;
        int j = i & 7, lane = (i >> 3) & 63, nt = (i >> 9) & 1, kstep = (i >> 10) & 1;
        int oc = nt * 16 + (lane & 15);
        int ky = (lane >> 4) & 3, kx = j & 3;
        float v;
        if (kstep == 0) { int ic = j >> 2; v = w1[oc * 48 + ic * 16 + ky * 4 + kx]; }
        else            { v = (j >> 2) == 0 ? w1[oc * 48 + 32 + ky * 4 + kx] : 0.f; }
        w1f[i] = f2bf(v);
    }
}

// ---------------- conv1 as implicit GEMM, bf16 MFMA ----------------
__global__ __launch_bounds__(256) void conv1_mfma(const float* __restrict__ x,
                                                  const float* __restrict__ b1,
                                                  const unsigned short* __restrict__ w1f,
                                                  unsigned short* __restrict__ h1b) {
    __shared__ unsigned int xs32[3 * 2046];        // 24.6 KB
    int img = blockIdx.x;
    int tid = threadIdx.x;
    const float* xg = x + (size_t)img * 11532;
    for (int d = tid; d < 5766; d += 256) {
        int c = d / 1922, r = d - c * 1922;
        int y = r / 31, xd = r - y * 31;
        const float* s = xg + c * 3844 + y * 62 + xd * 2;
        unsigned int lo = f2bf(s[0]), hi = f2bf(s[1]);
        xs32[c * 2046 + y * 33 + xd] = lo | (hi << 16);
    }
    __syncthreads();

    int lane = tid & 63, wid = tid >> 6;
    int rowl = lane & 15, g = lane >> 4;

    short8 bfr[2][2];
    #pragma unroll
    for (int ks = 0; ks < 2; ++ks)
        #pragma unroll
        for (int nt = 0; nt < 2; ++nt)
            bfr[ks][nt] = *(const short8*)(w1f + (((ks * 2 + nt) * 64 + lane) << 3));
    float bias0 = b1[rowl], bias1 = b1[16 + rowl];

    for (int i = 0; i < 15; ++i) {
        int mtile = wid + 4 * i;
        if (mtile >= 57) break;
        int m = mtile * 16 + rowl; if (m > 899) m = 899;
        int oy = m / 30, ox = m - oy * 30;
        int dof = (2 * oy + g) * 33 + ox;
        union { unsigned int u[4]; short8 s; } af0, af1;
        af0.u[0] = xs32[dof];          af0.u[1] = xs32[dof + 1];
        af0.u[2] = xs32[2046 + dof];   af0.u[3] = xs32[2046 + dof + 1];
        af1.u[0] = xs32[4092 + dof];   af1.u[1] = xs32[4092 + dof + 1];
        af1.u[2] = 0;                  af1.u[3] = 0;
        f32x4 acc0 = (f32x4){0.f, 0.f, 0.f, 0.f};
        f32x4 acc1 = (f32x4){0.f, 0.f, 0.f, 0.f};
        acc0 = __builtin_amdgcn_mfma_f32_16x16x32_bf16(af0.s, bfr[0][0], acc0, 0, 0, 0);
        acc0 = __builtin_amdgcn_mfma_f32_16x16x32_bf16(af1.s, bfr[1][0], acc0, 0, 0, 0);
        acc1 = __builtin_amdgcn_mfma_f32_16x16x32_bf16(af0.s, bfr[0][1], acc1, 0, 0, 0);
        acc1 = __builtin_amdgcn_mfma_f32_16x16x32_bf16(af1.s, bfr[1][1], acc1, 0, 0, 0);
        int sp0 = mtile * 16 + g * 4;
        #pragma unroll
        for (int nt = 0; nt < 2; ++nt) {
            f32x4 a = nt ? acc1 : acc0;
            int oc = nt * 16 + rowl;
            float bias = nt ? bias1 : bias0;
            unsigned short pk[4];
            #pragma unroll
            for (int r = 0; r < 4; ++r) pk[r] = f2bf(fmaxf(a[r] + bias, 0.f));
            unsigned short* dstp = h1b + (size_t)img * 28800 + oc * 900 + sp0;
            if (sp0 + 3 < 900) {
                *(uint2*)dstp = *(uint2*)pk;
            } else {
                #pragma unroll
                for (int r = 0; r < 4; ++r) if (sp0 + r < 900) dstp[r] = pk[r];
            }
        }
    }
}

// ---------------- conv2 as implicit GEMM, bf16 MFMA ----------------
__global__ __launch_bounds__(256) void conv2_mfma(const unsigned short* __restrict__ h1b,
                                                  const float* __restrict__ b2,
                                                  const unsigned short* __restrict__ w2f,
                                                  unsigned short* __restrict__ featb) {
    __shared__ unsigned short h1s[32 * 30 * 32];   // [ic][y][x pad 32] = 60 KB
    int img = blockIdx.x;
    int tid = threadIdx.x;
    {
        const unsigned int* src = (const unsigned int*)(h1b + (size_t)img * 28800);
        unsigned int* dst = (unsigned int*)h1s;
        for (int d = tid; d < 14400; d += 256) {
            int ic = d / 450, r = d - ic * 450;
            int y = r / 15, x2 = r - y * 15;
            dst[(ic * 30 + y) * 16 + x2] = src[d];
        }
    }
    __syncthreads();
    int lane = tid & 63, wid = tid >> 6;
    int rowl = lane & 15, g = lane >> 4;

    f32x4 acc[4][4];
    #pragma unroll
    for (int i = 0; i < 4; ++i)
        #pragma unroll
        for (int nt = 0; nt < 4; ++nt) acc[i][nt] = (f32x4){0.f, 0.f, 0.f, 0.f};

    int dofs[4];
    #pragma unroll
    for (int i = 0; i < 4; ++i) {
        int mtile = wid + 4 * i;
        int m = mtile * 16 + rowl; if (m > 195) m = 195;
        int oy = m / 14, ox = m - oy * 14;
        int y = 2 * oy + g, x0 = 2 * ox;
        dofs[i] = y * 16 + (x0 >> 1);
    }
    const unsigned int* lds32 = (const unsigned int*)h1s;

    #pragma unroll 4
    for (int kstep = 0; kstep < 16; ++kstep) {
        short8 bfr[4];
        #pragma unroll
        for (int nt = 0; nt < 4; ++nt)
            bfr[nt] = *(const short8*)(w2f + (((nt * 16 + kstep) * 64 + lane) << 3));
        int icb = kstep * 960;
        #pragma unroll
        for (int i = 0; i < 4; ++i) {
            int mtile = wid + 4 * i;
            if (mtile < 13) {
                int dof = icb + dofs[i];
                union { unsigned int u[4]; short8 s; } af;
                af.u[0] = lds32[dof];
                af.u[1] = lds32[dof + 1];
                af.u[2] = lds32[dof + 480];
                af.u[3] = lds32[dof + 481];
                #pragma unroll
                for (int nt = 0; nt < 4; ++nt)
                    acc[i][nt] = __builtin_amdgcn_mfma_f32_16x16x32_bf16(af.s, bfr[nt], acc[i][nt], 0, 0, 0);
            }
        }
    }
    #pragma unroll
    for (int i = 0; i < 4; ++i) {
        int mtile = wid + 4 * i;
        if (mtile >= 13) continue;
        int sp0 = mtile * 16 + g * 4;
        #pragma unroll
        for (int nt = 0; nt < 4; ++nt) {
            int oc = nt * 16 + rowl;
            float bias = b2[oc];
            unsigned short pk[4];
            #pragma unroll
            for (int r = 0; r < 4; ++r)
                pk[r] = f2bf(fmaxf(acc[i][nt][r] + bias, 0.f));
            unsigned short* dstp = featb + (size_t)img * 12544 + oc * 196 + sp0;
            if (sp0 + 3 < 196) {
                *(uint2*)dstp = *(uint2*)pk;
            } else {
                #pragma unroll
                for (int r = 0; r < 4; ++r) if (sp0 + r < 196) dstp[r] = pk[r];
            }
        }
    }
}

// ---------------- u = feat @ W_in : bf16 MFMA, split-K=28 ----------------
__global__ __launch_bounds__(256) void gemm_u_mfma(const unsigned short* __restrict__ featb,
                                                   const unsigned short* __restrict__ Wbbf,
                                                   float* __restrict__ part) {
    int tid = threadIdx.x, lane = tid & 63, wid = tid >> 6;
    int rowl = lane & 15, g = lane >> 4;
    int m0 = blockIdx.x * 64 + wid * 16;
    int ks0 = blockIdx.y * 14;
    f32x4 acc[8];
    #pragma unroll
    for (int nt = 0; nt < 8; ++nt) acc[nt] = (f32x4){0.f, 0.f, 0.f, 0.f};
    const unsigned short* arow = featb + (size_t)(m0 + rowl) * FEATN + g * 8;
    #pragma unroll 2
    for (int kk = 0; kk < 14; ++kk) {
        int kstep = ks0 + kk;
        short8 afr = *(const short8*)(arow + kstep * 32);
        #pragma unroll
        for (int nt = 0; nt < 8; ++nt) {
            short8 bfr = *(const short8*)(Wbbf + ((((size_t)kstep * 8 + nt) * 64 + lane) << 3));
            acc[nt] = __builtin_amdgcn_mfma_f32_16x16x32_bf16(afr, bfr, acc[nt], 0, 0, 0);
        }
    }
    float* pg = part + (size_t)blockIdx.y * 131072;
    #pragma unroll
    for (int nt = 0; nt < 8; ++nt)
        #pragma unroll
        for (int r = 0; r < 4; ++r)
            pg[(m0 + g * 4 + r) * 128 + nt * 16 + rowl] = acc[nt][r];
}

// reduce into u laid out [bg(4)][t(64)][c(128)][q(4)]  (q = batch within group)
__global__ void reduce_u(const float* __restrict__ part, const float* __restrict__ bbb,
                         float* __restrict__ u) {
    int o = blockIdx.x * 256 + threadIdx.x;   // 131072 total
    int q = o & 3, c = (o >> 2) & 127, t = (o >> 9) & 63, bg = o >> 15;
    int m = (bg * 4 + q) * 64 + t;            // image row = batch*64 + t
    float s = bbb[c];
    #pragma unroll
    for (int ks = 0; ks < 28; ++ks) s += part[(size_t)ks * 131072 + m * 128 + c];
    u[o] = s;
}

// ---------------- liquid RNN: 4 blocks x 4 batches, 2 waves, u fully in LDS ----------------
// Phase1: z[16][128] = lecun_tanh(u_t + hid@Wh); wave w covers z cols [64w,64w+63] (ntl 0..3).
// Phase2: [ff1|ff2|ta|tb] = z @ Wg; wave w covers cols [32w,32w+31] of each matrix (ntc 0..1).
// hid/z pass through MFMA as split-bf16 hi+lo, packed one dword per value.
// No global traffic inside the loop -> __syncthreads has nothing to drain.
__global__ __launch_bounds__(128, 1) void rnn_mfma(const float* __restrict__ u,
                                                   const unsigned short* __restrict__ whf,
                                                   const unsigned short* __restrict__ wgf,
                                                   const float* __restrict__ bff1,
                                                   const float* __restrict__ bff2,
                                                   const float* __restrict__ bta,
                                                   const float* __restrict__ btb,
                                                   const float* __restrict__ Wout,
                                                   const float* __restrict__ bout,
                                                   float* __restrict__ out) {
    __shared__ float u_s[64 * 128 * 4];        // 128 KB  [t][c][q]
    __shared__ unsigned int zP[16 * 132];      // 8448 B, packed lo<<16|hi
    __shared__ unsigned int hidP[16 * 68];     // 4352 B
    int tid = threadIdx.x, lane = tid & 63, w = tid >> 6;   // w in {0,1}
    int rowl = lane & 15, g = lane >> 4;
    int bk = blockIdx.x;                        // batch group 0..3

    // preload this group's u slab (contiguous 128 KB), init hid
    {
        const float4* src = (const float4*)(u + (size_t)bk * 32768);
        float4* dst = (float4*)u_s;
        for (int i = tid; i < 8192; i += 128) dst[i] = src[i];
    }
    for (int i = tid; i < 16 * 68; i += 128) hidP[i] = 0;

    // B-fragments -> registers (once)
    short8 wh_r[2][4];   // [ks][ntl], nt_abs = 4w + ntl
    #pragma unroll
    for (int ks = 0; ks < 2; ++ks)
        #pragma unroll
        for (int ntl = 0; ntl < 4; ++ntl)
            wh_r[ks][ntl] = *(const short8*)(whf + (((ks * 8 + 4 * w + ntl) * 64 + lane) << 3));
    short8 wg_r[4][2][4];   // [m][ntc][ks], nt_abs = m*4 + 2w + ntc
    #pragma unroll
    for (int m = 0; m < 4; ++m)
        #pragma unroll
        for (int ntc = 0; ntc < 2; ++ntc)
            #pragma unroll
            for (int ks = 0; ks < 4; ++ks)
                wg_r[m][ntc][ks] = *(const short8*)(wgf + (((ks * 16 + m * 4 + 2 * w + ntc) * 64 + lane) << 3));

    int cc0 = (2 * w) * 16 + rowl, cc1 = (2 * w + 1) * 16 + rowl;
    float b1v[2] = {bff1[cc0], bff1[cc1]};
    float b2v[2] = {bff2[cc0], bff2[cc1]};
    float btv[2] = {bta[cc0] + btb[cc0], bta[cc1] + btb[cc1]};

    __syncthreads();

    float hidv[2][4];
    #pragma unroll 1
    for (int t = 0; t < 64; ++t) {
        // ---- Phase 1: z = lecun_tanh(u_t + hid @ Wh) ----
        short8 ah[2], al[2];
        #pragma unroll
        for (int ks = 0; ks < 2; ++ks) {
            const unsigned int* p = &hidP[rowl * 68 + ks * 32 + g * 8];
            unpack8(*(const uint4*)p, *(const uint4*)(p + 4), &ah[ks], &al[ks]);
        }
        f32x4 za[4], zb[4];
        #pragma unroll
        for (int ntl = 0; ntl < 4; ++ntl) {
            if (g == 0) {
                float4 uv = *(const float4*)&u_s[(t * 128 + (4 * w + ntl) * 16 + rowl) * 4];
                za[ntl] = (f32x4){uv.x, uv.y, uv.z, uv.w};
            } else {
                za[ntl] = (f32x4){0.f, 0.f, 0.f, 0.f};
            }
            za[ntl] = __builtin_amdgcn_mfma_f32_16x16x32_bf16(al[0], wh_r[0][ntl], za[ntl], 0, 0, 0);
            za[ntl] = __builtin_amdgcn_mfma_f32_16x16x32_bf16(al[1], wh_r[1][ntl], za[ntl], 0, 0, 0);
            zb[ntl] = (f32x4){0.f, 0.f, 0.f, 0.f};
            zb[ntl] = __builtin_amdgcn_mfma_f32_16x16x32_bf16(ah[0], wh_r[0][ntl], zb[ntl], 0, 0, 0);
            zb[ntl] = __builtin_amdgcn_mfma_f32_16x16x32_bf16(ah[1], wh_r[1][ntl], zb[ntl], 0, 0, 0);
        }
        #pragma unroll
        for (int ntl = 0; ntl < 4; ++ntl) {
            #pragma unroll
            for (int r = 0; r < 4; ++r) {
                float zv = 1.7159f * fast_tanh(0.666f * (za[ntl][r] + zb[ntl][r]));
                unsigned int hi = f2bf(zv);
                unsigned int lo = f2bf(zv - bf2f((unsigned short)hi));
                zP[(g * 4 + r) * 132 + (4 * w + ntl) * 16 + rowl] = hi | (lo << 16);
            }
        }
        __syncthreads();
        // ---- Phase 2: [ff1|ff2|ta|tb] = z @ Wg ----
        short8 zh[4], zl[4];
        #pragma unroll
        for (int ks = 0; ks < 4; ++ks) {
            const unsigned int* p = &zP[rowl * 132 + ks * 32 + g * 8];
            unpack8(*(const uint4*)p, *(const uint4*)(p + 4), &zh[ks], &zl[ks]);
        }
        f32x4 facc[4][2];
        #pragma unroll
        for (int ntc = 0; ntc < 2; ++ntc) {
            facc[0][ntc] = (f32x4){b1v[ntc], b1v[ntc], b1v[ntc], b1v[ntc]};
            facc[1][ntc] = (f32x4){b2v[ntc], b2v[ntc], b2v[ntc], b2v[ntc]};
            facc[2][ntc] = (f32x4){btv[ntc], btv[ntc], btv[ntc], btv[ntc]};
            facc[3][ntc] = (f32x4){0.f, 0.f, 0.f, 0.f};
        }
        #pragma unroll
        for (int m = 0; m < 4; ++m)
            #pragma unroll
            for (int ntc = 0; ntc < 2; ++ntc)
                #pragma unroll
                for (int ks = 0; ks < 4; ++ks) {
                    facc[m][ntc] = __builtin_amdgcn_mfma_f32_16x16x32_bf16(zl[ks], wg_r[m][ntc][ks], facc[m][ntc], 0, 0, 0);
                    facc[m][ntc] = __builtin_amdgcn_mfma_f32_16x16x32_bf16(zh[ks], wg_r[m][ntc][ks], facc[m][ntc], 0, 0, 0);
                }
        #pragma unroll
        for (int ntc = 0; ntc < 2; ++ntc) {
            int cc = ntc ? cc1 : cc0;
            #pragma unroll
            for (int r = 0; r < 4; ++r) {
                float f1 = fast_tanh(facc[0][ntc][r]);
                float f2 = fast_tanh(facc[1][ntc][r]);
                float tt = fast_sigmoid(facc[2][ntc][r] + facc[3][ntc][r]);
                float hv = f1 * (1.f - tt) + tt * f2;
                hidv[ntc][r] = hv;
                unsigned int hi = f2bf(hv);
                unsigned int lo = f2bf(hv - bf2f((unsigned short)hi));
                hidP[(g * 4 + r) * 68 + cc] = hi | (lo << 16);
            }
        }
        __syncthreads();
    }

    // fused head: hid[4][64] @ Wout[64][8] + bout  (reuse zP as f32 buffer)
    float* hf = (float*)zP;
    if (g == 0) {
        #pragma unroll
        for (int ntc = 0; ntc < 2; ++ntc) {
            int cc = ntc ? cc1 : cc0;
            #pragma unroll
            for (int r = 0; r < 4; ++r) hf[r * 64 + cc] = hidv[ntc][r];
        }
    }
    __syncthreads();
    if (tid < 32) {
        int b = tid >> 3, a = tid & 7;
        float s = bout[a];
        #pragma unroll
        for (int j = 0; j < 64; ++j) s += hf[b * 64 + j] * Wout[j * 8 + a];
        out[(bk * 4 + b) * 8 + a] = s;
    }
}

extern "C" void kernel_launch(void* const* d_in, const int* in_sizes, int n_in,
                              void* d_out, int out_size, void* d_ws, size_t ws_size,
                              hipStream_t stream) {
    const float* x    = (const float*)d_in[0];
    const float* w1   = (const float*)d_in[1];
    const float* b1   = (const float*)d_in[2];
    const float* w2   = (const float*)d_in[3];
    const float* b2   = (const float*)d_in[4];
    const float* Wbb  = (const float*)d_in[5];
    const float* bbb  = (const float*)d_in[6];
    const float* Wff1 = (const float*)d_in[7];
    const float* bff1 = (const float*)d_in[8];
    const float* Wff2 = (const float*)d_in[9];
    const float* bff2 = (const float*)d_in[10];
    const float* Wta  = (const float*)d_in[11];
    const float* bta  = (const float*)d_in[12];
    const float* Wtb  = (const float*)d_in[13];
    const float* btb  = (const float*)d_in[14];
    const float* Wout = (const float*)d_in[15];
    const float* bout = (const float*)d_in[16];

    if (ws_size < (size_t)WS_BYTES) return;

    char* wsb = (char*)d_ws;
    unsigned short* w1f   = (unsigned short*)(wsb + OFF_W1F);
    unsigned short* w2f   = (unsigned short*)(wsb + OFF_W2F);
    unsigned short* wbbf  = (unsigned short*)(wsb + OFF_WBBF);
    unsigned short* h1b   = (unsigned short*)(wsb + OFF_H1B);
    unsigned short* featb = (unsigned short*)(wsb + OFF_FEATB);
    float*          u     = (float*)(wsb + OFF_U);
    float*          part  = (float*)(wsb + OFF_PART);
    unsigned short* whf   = (unsigned short*)(wsb + OFF_WHF);
    unsigned short* wgf   = (unsigned short*)(wsb + OFF_WGF);

    prep_all<<<6568, 256, 0, stream>>>(w1, w2, Wbb, Wff1, Wff2, Wta, Wtb,
                                       w1f, w2f, wbbf, whf, wgf);
    conv1_mfma<<<1024, 256, 0, stream>>>(x, b1, w1f, h1b);
    conv2_mfma<<<1024, 256, 0, stream>>>(h1b, b2, w2f, featb);
    gemm_u_mfma<<<dim3(16, 28), 256, 0, stream>>>(featb, wbbf, part);
    reduce_u<<<512, 256, 0, stream>>>(part, bbb, u);
    rnn_mfma<<<4, 128, 0, stream>>>(u, whf, wgf, bff1, bff2, bta, btb, Wout, bout, (float*)d_out);
}

// Round 10
// 170.815 us; speedup vs baseline: 1.4749x; 1.4749x over previous
//
#include <hip/hip_runtime.h>
#include <hip/hip_bf16.h>
#include <math.h>

#define FEATN 12544
#define NIMG 1024

typedef __attribute__((ext_vector_type(8))) short short8;
typedef __attribute__((ext_vector_type(4))) float f32x4;

// ---- ws byte offsets (all sizes in BYTES; bf16 regions are 2 B/elem) ----
#define OFF_W1F   0            //  2048 bf16  =     4096 B   conv1 B-frag table
#define OFF_W2F   6144         //  32768 bf16 =    65536 B   conv2 B-frag table
#define OFF_WBBF  71680        //  1605632 bf16 = 3211264 B  gemm_u B-frag table
#define OFF_H1B   3282944      //  1024*28800 bf16 = 58982400 B
#define OFF_FEATB 62265344     //  1024*12544 bf16 = 25690112 B
#define OFF_U     87955456     //  131072 f32 = 524288 B   (layout [t][b][128])
#define OFF_PART  88479744     //  28*131072 f32 = 14680064 B
#define OFF_HID   103159808    //  1024 f32 = 4096 B
#define OFF_WHF   103163904    //  8192 bf16 = 16384 B   rnn Wh B-frag table
#define OFF_WGF   103180288    //  32768 bf16 = 65536 B  rnn [ff1|ff2|ta|tb] B-frag table
#define WS_BYTES  103245824

__device__ __forceinline__ unsigned short f2bf(float v) {
    union { float f; unsigned int u; } c; c.f = v;
    unsigned int r = c.u + 0x7FFFu + ((c.u >> 16) & 1u);   // RNE
    return (unsigned short)(r >> 16);
}
__device__ __forceinline__ float bf2f(unsigned short h) {
    union { unsigned int u; float f; } c; c.u = ((unsigned int)h) << 16;
    return c.f;
}

__device__ __forceinline__ float fast_tanh(float x) {
    x = fminf(fmaxf(x, -15.f), 15.f);
    float e = __expf(2.f * x);
    return (e - 1.f) * __builtin_amdgcn_rcpf(e + 1.f);
}
__device__ __forceinline__ float fast_sigmoid(float x) {
    x = fminf(fmaxf(x, -30.f), 30.f);
    return __builtin_amdgcn_rcpf(1.f + __expf(-x));
}

// ---------------- merged weight-prep kernel (5-in-1) ----------------
__global__ __launch_bounds__(256) void prep_all(const float* __restrict__ w1, const float* __restrict__ w2,
                         const float* __restrict__ Wbb,
                         const float* __restrict__ Wff1, const float* __restrict__ Wff2,
                         const float* __restrict__ Wta,  const float* __restrict__ Wtb,
                         unsigned short* __restrict__ w1f, unsigned short* __restrict__ w2f,
                         unsigned short* __restrict__ wbbf,
                         unsigned short* __restrict__ whf, unsigned short* __restrict__ wgf) {
    int bid = blockIdx.x, tid = threadIdx.x;
    if (bid < 6272) {                       // Wbb(feat) -> wbbf, 1605632
        int i = bid * 256 + tid;
        int j = i & 7, lane = (i >> 3) & 63, nt = (i >> 9) & 7, kstep = i >> 12;
        int f = kstep * 32 + (lane >> 4) * 8 + j;
        int col = nt * 16 + (lane & 15);
        wbbf[i] = f2bf(Wbb[(size_t)f * 128 + col]);
    } else if (bid < 6400) {                // w2 -> w2f, 32768
        int i = (bid - 6272) * 256 + tid;
        int j = i & 7, lane = (i >> 3) & 63, kstep = (i >> 9) & 15, nt = i >> 13;
        int oc = nt * 16 + (lane & 15);
        int ic = 2 * kstep + (j >> 2);
        int ky = lane >> 4, kx = j & 3;
        w2f[i] = f2bf(w2[oc * 512 + ic * 16 + ky * 4 + kx]);
    } else if (bid < 6528) {                // gates -> wgf, 32768
        int i = (bid - 6400) * 256 + tid;
        int j = i & 7, lane = (i >> 3) & 63, nt = (i >> 9) & 15, kstep = (i >> 13) & 3;
        int k = kstep * 32 + ((lane >> 4) & 3) * 8 + j;
        int m = nt >> 2;
        int c = (nt & 3) * 16 + (lane & 15);
        const float* Wm = (m == 0) ? Wff1 : (m == 1) ? Wff2 : (m == 2) ? Wta : Wtb;
        wgf[i] = f2bf(Wm[k * 64 + c]);
    } else if (bid < 6560) {                // Wh -> whf, 8192
        int i = (bid - 6528) * 256 + tid;
        int j = i & 7, lane = (i >> 3) & 63, nt = (i >> 9) & 7, kstep = (i >> 12) & 1;
        int k = kstep * 32 + ((lane >> 4) & 3) * 8 + j;
        int col = nt * 16 + (lane & 15);
        whf[i] = f2bf(Wbb[(size_t)(FEATN + k) * 128 + col]);
    } else {                                // w1 -> w1f, 2048
        int i = (bid - 6560) * 256 + tid;
        if (i >= 2048) return;
        int j = i & 7, lane = (i >> 3) & 63, nt = (i >> 9) & 1, kstep = (i >> 10) & 1;
        int oc = nt * 16 + (lane & 15);
        int ky = (lane >> 4) & 3, kx = j & 3;
        float v;
        if (kstep == 0) { int ic = j >> 2; v = w1[oc * 48 + ic * 16 + ky * 4 + kx]; }
        else            { v = (j >> 2) == 0 ? w1[oc * 48 + 32 + ky * 4 + kx] : 0.f; }
        w1f[i] = f2bf(v);
    }
}

// ---------------- conv1 as implicit GEMM, bf16 MFMA ----------------
__global__ __launch_bounds__(256) void conv1_mfma(const float* __restrict__ x,
                                                  const float* __restrict__ b1,
                                                  const unsigned short* __restrict__ w1f,
                                                  unsigned short* __restrict__ h1b) {
    __shared__ unsigned int xs32[3 * 2046];        // 24.6 KB
    int img = blockIdx.x;
    int tid = threadIdx.x;
    const float* xg = x + (size_t)img * 11532;
    for (int d = tid; d < 5766; d += 256) {
        int c = d / 1922, r = d - c * 1922;
        int y = r / 31, xd = r - y * 31;
        const float* s = xg + c * 3844 + y * 62 + xd * 2;
        unsigned int lo = f2bf(s[0]), hi = f2bf(s[1]);
        xs32[c * 2046 + y * 33 + xd] = lo | (hi << 16);
    }
    __syncthreads();

    int lane = tid & 63, wid = tid >> 6;
    int rowl = lane & 15, g = lane >> 4;

    short8 bfr[2][2];
    #pragma unroll
    for (int ks = 0; ks < 2; ++ks)
        #pragma unroll
        for (int nt = 0; nt < 2; ++nt)
            bfr[ks][nt] = *(const short8*)(w1f + (((ks * 2 + nt) * 64 + lane) << 3));
    float bias0 = b1[rowl], bias1 = b1[16 + rowl];

    for (int i = 0; i < 15; ++i) {
        int mtile = wid + 4 * i;
        if (mtile >= 57) break;
        int m = mtile * 16 + rowl; if (m > 899) m = 899;
        int oy = m / 30, ox = m - oy * 30;
        int dof = (2 * oy + g) * 33 + ox;
        union { unsigned int u[4]; short8 s; } af0, af1;
        af0.u[0] = xs32[dof];          af0.u[1] = xs32[dof + 1];
        af0.u[2] = xs32[2046 + dof];   af0.u[3] = xs32[2046 + dof + 1];
        af1.u[0] = xs32[4092 + dof];   af1.u[1] = xs32[4092 + dof + 1];
        af1.u[2] = 0;                  af1.u[3] = 0;
        f32x4 acc0 = (f32x4){0.f, 0.f, 0.f, 0.f};
        f32x4 acc1 = (f32x4){0.f, 0.f, 0.f, 0.f};
        acc0 = __builtin_amdgcn_mfma_f32_16x16x32_bf16(af0.s, bfr[0][0], acc0, 0, 0, 0);
        acc0 = __builtin_amdgcn_mfma_f32_16x16x32_bf16(af1.s, bfr[1][0], acc0, 0, 0, 0);
        acc1 = __builtin_amdgcn_mfma_f32_16x16x32_bf16(af0.s, bfr[0][1], acc1, 0, 0, 0);
        acc1 = __builtin_amdgcn_mfma_f32_16x16x32_bf16(af1.s, bfr[1][1], acc1, 0, 0, 0);
        int sp0 = mtile * 16 + g * 4;
        #pragma unroll
        for (int nt = 0; nt < 2; ++nt) {
            f32x4 a = nt ? acc1 : acc0;
            int oc = nt * 16 + rowl;
            float bias = nt ? bias1 : bias0;
            unsigned short pk[4];
            #pragma unroll
            for (int r = 0; r < 4; ++r) pk[r] = f2bf(fmaxf(a[r] + bias, 0.f));
            unsigned short* dstp = h1b + (size_t)img * 28800 + oc * 900 + sp0;
            if (sp0 + 3 < 900) {
                *(uint2*)dstp = *(uint2*)pk;
            } else {
                #pragma unroll
                for (int r = 0; r < 4; ++r) if (sp0 + r < 900) dstp[r] = pk[r];
            }
        }
    }
}

// ---------------- conv2 as implicit GEMM, bf16 MFMA ----------------
// Staging now via global_load_lds dwordx4: LDS dest linear over padded [ic][y][16]
// layout; per-lane global source pre-swizzled (pad dword x2=15 gets harmless
// garbage from the next source row; reads only touch x2<=14).
__global__ __launch_bounds__(256) void conv2_mfma(const unsigned short* __restrict__ h1b,
                                                  const float* __restrict__ b2,
                                                  const unsigned short* __restrict__ w2f,
                                                  unsigned short* __restrict__ featb) {
    __shared__ unsigned short h1s[32 * 30 * 32];   // [ic][y][x pad 32] = 61440 B = 15360 dwords
    int img = blockIdx.x;
    int tid = threadIdx.x;
    int lane = tid & 63, wid = tid >> 6;
    {
        const unsigned int* src = (const unsigned int*)(h1b + (size_t)img * 28800);
        unsigned int* dst = (unsigned int*)h1s;
        #pragma unroll
        for (int i = 0; i < 15; ++i) {
            int Q = (i * 4 + wid) * 64 + lane;       // quad index 0..3839
            int D0 = Q << 2;                          // dest dword
            int ic = D0 / 480;
            int rem = D0 - ic * 480;
            int y = rem >> 4, x2 = rem & 15;          // x2 in {0,4,8,12}
            const unsigned int* g = src + ic * 450 + y * 15 + x2;
            __builtin_amdgcn_global_load_lds(
                (const __attribute__((address_space(1))) unsigned int*)g,
                (__attribute__((address_space(3))) unsigned int*)(dst + ((i * 4 + wid) << 8)),
                16, 0, 0);
        }
    }
    __syncthreads();
    int rowl = lane & 15, g = lane >> 4;

    f32x4 acc[4][4];
    #pragma unroll
    for (int i = 0; i < 4; ++i)
        #pragma unroll
        for (int nt = 0; nt < 4; ++nt) acc[i][nt] = (f32x4){0.f, 0.f, 0.f, 0.f};

    int dofs[4];
    #pragma unroll
    for (int i = 0; i < 4; ++i) {
        int mtile = wid + 4 * i;
        int m = mtile * 16 + rowl; if (m > 195) m = 195;
        int oy = m / 14, ox = m - oy * 14;
        int y = 2 * oy + g, x0 = 2 * ox;
        dofs[i] = y * 16 + (x0 >> 1);
    }
    const unsigned int* lds32 = (const unsigned int*)h1s;

    #pragma unroll 4
    for (int kstep = 0; kstep < 16; ++kstep) {
        short8 bfr[4];
        #pragma unroll
        for (int nt = 0; nt < 4; ++nt)
            bfr[nt] = *(const short8*)(w2f + (((nt * 16 + kstep) * 64 + lane) << 3));
        int icb = kstep * 960;
        #pragma unroll
        for (int i = 0; i < 4; ++i) {
            int mtile = wid + 4 * i;
            if (mtile < 13) {
                int dof = icb + dofs[i];
                union { unsigned int u[4]; short8 s; } af;
                af.u[0] = lds32[dof];
                af.u[1] = lds32[dof + 1];
                af.u[2] = lds32[dof + 480];
                af.u[3] = lds32[dof + 481];
                #pragma unroll
                for (int nt = 0; nt < 4; ++nt)
                    acc[i][nt] = __builtin_amdgcn_mfma_f32_16x16x32_bf16(af.s, bfr[nt], acc[i][nt], 0, 0, 0);
            }
        }
    }
    #pragma unroll
    for (int i = 0; i < 4; ++i) {
        int mtile = wid + 4 * i;
        if (mtile >= 13) continue;
        int sp0 = mtile * 16 + g * 4;
        #pragma unroll
        for (int nt = 0; nt < 4; ++nt) {
            int oc = nt * 16 + rowl;
            float bias = b2[oc];
            unsigned short pk[4];
            #pragma unroll
            for (int r = 0; r < 4; ++r)
                pk[r] = f2bf(fmaxf(acc[i][nt][r] + bias, 0.f));
            unsigned short* dstp = featb + (size_t)img * 12544 + oc * 196 + sp0;
            if (sp0 + 3 < 196) {
                *(uint2*)dstp = *(uint2*)pk;
            } else {
                #pragma unroll
                for (int r = 0; r < 4; ++r) if (sp0 + r < 196) dstp[r] = pk[r];
            }
        }
    }
}

// ---------------- u = feat @ W_in : bf16 MFMA, split-K=28 ----------------
__global__ __launch_bounds__(256) void gemm_u_mfma(const unsigned short* __restrict__ featb,
                                                   const unsigned short* __restrict__ Wbbf,
                                                   float* __restrict__ part) {
    int tid = threadIdx.x, lane = tid & 63, wid = tid >> 6;
    int rowl = lane & 15, g = lane >> 4;
    int m0 = blockIdx.x * 64 + wid * 16;
    int ks0 = blockIdx.y * 14;
    f32x4 acc[8];
    #pragma unroll
    for (int nt = 0; nt < 8; ++nt) acc[nt] = (f32x4){0.f, 0.f, 0.f, 0.f};
    const unsigned short* arow = featb + (size_t)(m0 + rowl) * FEATN + g * 8;
    #pragma unroll 2
    for (int kk = 0; kk < 14; ++kk) {
        int kstep = ks0 + kk;
        short8 afr = *(const short8*)(arow + kstep * 32);
        #pragma unroll
        for (int nt = 0; nt < 8; ++nt) {
            short8 bfr = *(const short8*)(Wbbf + ((((size_t)kstep * 8 + nt) * 64 + lane) << 3));
            acc[nt] = __builtin_amdgcn_mfma_f32_16x16x32_bf16(afr, bfr, acc[nt], 0, 0, 0);
        }
    }
    float* pg = part + (size_t)blockIdx.y * 131072;
    #pragma unroll
    for (int nt = 0; nt < 8; ++nt)
        #pragma unroll
        for (int r = 0; r < 4; ++r)
            pg[(m0 + g * 4 + r) * 128 + nt * 16 + rowl] = acc[nt][r];
}

// reduce into u laid out [t][b][128]
__global__ void reduce_u(const float* __restrict__ part, const float* __restrict__ bbb,
                         float* __restrict__ u) {
    int o = blockIdx.x * 256 + threadIdx.x;   // 131072 total
    int c = o & 127, b = (o >> 7) & 15, t = o >> 11;
    int m = b * 64 + t;
    float s = bbb[c];
    #pragma unroll
    for (int ks = 0; ks < 28; ++ks) s += part[(size_t)ks * 131072 + m * 128 + c];
    u[o] = s;
}

// ---------------- liquid RNN scan: batched MFMA (M=16 batches), 1 block, 4 waves ----------------
// R7-measured structure (90 us): plain __syncthreads, separate hi/lo LDS arrays,
// depth-1 u register prefetch, XOR-swizzled LDS (same involution both sides).
__global__ __launch_bounds__(256, 1) void rnn_mfma(const float* __restrict__ u,
                                                   const unsigned short* __restrict__ whf,
                                                   const unsigned short* __restrict__ wgf,
                                                   const float* __restrict__ bff1,
                                                   const float* __restrict__ bff2,
                                                   const float* __restrict__ bta,
                                                   const float* __restrict__ btb,
                                                   float* __restrict__ hid_out) {
    __shared__ unsigned short hidA_hi[16 * 64], hidA_lo[16 * 64];   // [row][k0..63]
    __shared__ unsigned short zA_hi[16 * 128], zA_lo[16 * 128];     // [row][k0..127]
    int tid = threadIdx.x, lane = tid & 63, w = tid >> 6;
    int rowl = lane & 15, g = lane >> 4;

    for (int idx = tid; idx < 1024; idx += 256) { hidA_hi[idx] = 0; hidA_lo[idx] = 0; }

    // B-fragments -> registers (once)
    short8 wh_r[2][2];   // [kstep][ntl], nt_abs = 2w + ntl
    #pragma unroll
    for (int ks = 0; ks < 2; ++ks)
        #pragma unroll
        for (int ntl = 0; ntl < 2; ++ntl)
            wh_r[ks][ntl] = *(const short8*)(whf + (((ks * 8 + 2 * w + ntl) * 64 + lane) << 3));
    short8 wg_r[4][4];   // [m][kstep], nt_abs = 4m + w
    #pragma unroll
    for (int m = 0; m < 4; ++m)
        #pragma unroll
        for (int ks = 0; ks < 4; ++ks)
            wg_r[m][ks] = *(const short8*)(wgf + (((ks * 16 + 4 * m + w) * 64 + lane) << 3));

    int cc = w * 16 + rowl;                   // this lane's phase-2 column
    float bias1 = bff1[cc], bias2 = bff2[cc], biast = bta[cc] + btb[cc];

    // u prefetch (t=0)
    float upf[8];
    #pragma unroll
    for (int i = 0; i < 8; ++i) {
        int ntl = i >> 2, r = i & 3;
        upf[i] = u[(g * 4 + r) * 128 + (2 * w + ntl) * 16 + rowl];
    }
    __syncthreads();

    float hidv[4];
    #pragma unroll 1
    for (int t = 0; t < 64; ++t) {
        // ---- Phase 1 ----
        short8 ah[2], al[2];
        #pragma unroll
        for (int ks = 0; ks < 2; ++ks) {
            int byte = (rowl * 128 + ks * 64 + g * 16) ^ ((rowl & 7) << 4);
            ah[ks] = *(const short8*)((const char*)hidA_hi + byte);
            al[ks] = *(const short8*)((const char*)hidA_lo + byte);
        }
        f32x4 zacc[2];
        #pragma unroll
        for (int ntl = 0; ntl < 2; ++ntl) {
            zacc[ntl] = (f32x4){upf[ntl * 4 + 0], upf[ntl * 4 + 1], upf[ntl * 4 + 2], upf[ntl * 4 + 3]};
            #pragma unroll
            for (int ks = 0; ks < 2; ++ks) {
                zacc[ntl] = __builtin_amdgcn_mfma_f32_16x16x32_bf16(al[ks], wh_r[ks][ntl], zacc[ntl], 0, 0, 0);
                zacc[ntl] = __builtin_amdgcn_mfma_f32_16x16x32_bf16(ah[ks], wh_r[ks][ntl], zacc[ntl], 0, 0, 0);
            }
        }
        // prefetch u for t+1 (overlaps rest of step)
        if (t < 63) {
            #pragma unroll
            for (int i = 0; i < 8; ++i) {
                int ntl = i >> 2, r = i & 3;
                upf[i] = u[(t + 1) * 2048 + (g * 4 + r) * 128 + (2 * w + ntl) * 16 + rowl];
            }
        }
        // tanh + write z (hi/lo) to LDS
        #pragma unroll
        for (int ntl = 0; ntl < 2; ++ntl)
            #pragma unroll
            for (int r = 0; r < 4; ++r) {
                float zv = 1.7159f * fast_tanh(0.666f * zacc[ntl][r]);
                int row = g * 4 + r, c = w * 32 + ntl * 16 + rowl;
                unsigned short zh = f2bf(zv);
                unsigned short zl = f2bf(zv - bf2f(zh));
                int byte = (row * 256 + c * 2) ^ ((row & 7) << 4);
                *(unsigned short*)((char*)zA_hi + byte) = zh;
                *(unsigned short*)((char*)zA_lo + byte) = zl;
            }
        __syncthreads();
        // ---- Phase 2 ----
        short8 zh[4], zl[4];
        #pragma unroll
        for (int ks = 0; ks < 4; ++ks) {
            int byte = (rowl * 256 + ks * 64 + g * 16) ^ ((rowl & 7) << 4);
            zh[ks] = *(const short8*)((const char*)zA_hi + byte);
            zl[ks] = *(const short8*)((const char*)zA_lo + byte);
        }
        f32x4 facc[4];
        facc[0] = (f32x4){bias1, bias1, bias1, bias1};
        facc[1] = (f32x4){bias2, bias2, bias2, bias2};
        facc[2] = (f32x4){biast, biast, biast, biast};
        facc[3] = (f32x4){0.f, 0.f, 0.f, 0.f};
        #pragma unroll
        for (int m = 0; m < 4; ++m)
            #pragma unroll
            for (int ks = 0; ks < 4; ++ks) {
                facc[m] = __builtin_amdgcn_mfma_f32_16x16x32_bf16(zl[ks], wg_r[m][ks], facc[m], 0, 0, 0);
                facc[m] = __builtin_amdgcn_mfma_f32_16x16x32_bf16(zh[ks], wg_r[m][ks], facc[m], 0, 0, 0);
            }
        // activations + hid (hi/lo) write
        #pragma unroll
        for (int r = 0; r < 4; ++r) {
            float ff1 = fast_tanh(facc[0][r]);
            float ff2 = fast_tanh(facc[1][r]);
            float tt  = fast_sigmoid(facc[2][r] + facc[3][r]);
            float hv  = ff1 * (1.f - tt) + tt * ff2;
            hidv[r] = hv;
            int row = g * 4 + r;
            unsigned short hh = f2bf(hv);
            unsigned short hl = f2bf(hv - bf2f(hh));
            int byte = (row * 128 + cc * 2) ^ ((row & 7) << 4);
            *(unsigned short*)((char*)hidA_hi + byte) = hh;
            *(unsigned short*)((char*)hidA_lo + byte) = hl;
        }
        __syncthreads();
    }
    #pragma unroll
    for (int r = 0; r < 4; ++r)
        hid_out[(g * 4 + r) * 64 + cc] = hidv[r];
}

// ---------------- head ----------------
__global__ void head_kernel(const float* __restrict__ hid, const float* __restrict__ Wout,
                            const float* __restrict__ bout, float* __restrict__ out) {
    int tid = threadIdx.x;           // 128 = 16*8
    int b = tid >> 3, a = tid & 7;
    float s = bout[a];
    #pragma unroll
    for (int j = 0; j < 64; ++j) s += hid[b * 64 + j] * Wout[j * 8 + a];
    out[tid] = s;
}

extern "C" void kernel_launch(void* const* d_in, const int* in_sizes, int n_in,
                              void* d_out, int out_size, void* d_ws, size_t ws_size,
                              hipStream_t stream) {
    const float* x    = (const float*)d_in[0];
    const float* w1   = (const float*)d_in[1];
    const float* b1   = (const float*)d_in[2];
    const float* w2   = (const float*)d_in[3];
    const float* b2   = (const float*)d_in[4];
    const float* Wbb  = (const float*)d_in[5];
    const float* bbb  = (const float*)d_in[6];
    const float* Wff1 = (const float*)d_in[7];
    const float* bff1 = (const float*)d_in[8];
    const float* Wff2 = (const float*)d_in[9];
    const float* bff2 = (const float*)d_in[10];
    const float* Wta  = (const float*)d_in[11];
    const float* bta  = (const float*)d_in[12];
    const float* Wtb  = (const float*)d_in[13];
    const float* btb  = (const float*)d_in[14];
    const float* Wout = (const float*)d_in[15];
    const float* bout = (const float*)d_in[16];

    if (ws_size < (size_t)WS_BYTES) return;

    char* wsb = (char*)d_ws;
    unsigned short* w1f   = (unsigned short*)(wsb + OFF_W1F);
    unsigned short* w2f   = (unsigned short*)(wsb + OFF_W2F);
    unsigned short* wbbf  = (unsigned short*)(wsb + OFF_WBBF);
    unsigned short* h1b   = (unsigned short*)(wsb + OFF_H1B);
    unsigned short* featb = (unsigned short*)(wsb + OFF_FEATB);
    float*          u     = (float*)(wsb + OFF_U);
    float*          part  = (float*)(wsb + OFF_PART);
    float*          hid   = (float*)(wsb + OFF_HID);
    unsigned short* whf   = (unsigned short*)(wsb + OFF_WHF);
    unsigned short* wgf   = (unsigned short*)(wsb + OFF_WGF);

    prep_all<<<6568, 256, 0, stream>>>(w1, w2, Wbb, Wff1, Wff2, Wta, Wtb,
                                       w1f, w2f, wbbf, whf, wgf);
    conv1_mfma<<<1024, 256, 0, stream>>>(x, b1, w1f, h1b);
    conv2_mfma<<<1024, 256, 0, stream>>>(h1b, b2, w2f, featb);
    gemm_u_mfma<<<dim3(16, 28), 256, 0, stream>>>(featb, wbbf, part);
    reduce_u<<<512, 256, 0, stream>>>(part, bbb, u);
    rnn_mfma<<<1, 256, 0, stream>>>(u, whf, wgf, bff1, bff2, bta, btb, hid);
    head_kernel<<<1, 128, 0, stream>>>(hid, Wout, bout, (float*)d_out);
}

// Round 12
// 161.527 us; speedup vs baseline: 1.5597x; 1.0575x over previous
//
#include <hip/hip_runtime.h>
#include <hip/hip_bf16.h>
#include <math.h>

#define FEATN 12544
#define NIMG 1024
#define PLANEP 482   // h1s per-ic plane pitch in dwords (482%32=2 -> spreads banks)

typedef __attribute__((ext_vector_type(8))) short short8;
typedef __attribute__((ext_vector_type(4))) float f32x4;

// ---- ws byte offsets (all sizes in BYTES; bf16 regions are 2 B/elem) ----
#define OFF_W1F   0            //  2048 bf16  =     4096 B   conv1 B-frag table
#define OFF_W2F   6144         //  32768 bf16 =    65536 B   conv2 B-frag table
#define OFF_WBBF  71680        //  1605632 bf16 = 3211264 B  gemm_u B-frag table
#define OFF_FEATB 62265344     //  1024*12544 bf16 = 25690112 B
#define OFF_U     87955456     //  131072 f32 = 524288 B   (layout [t][b][128])
#define OFF_PART  88479744     //  28*131072 f32 = 14680064 B
#define OFF_HID   103159808    //  1024 f32 = 4096 B
#define OFF_WHF   103163904    //  8192 bf16 = 16384 B   rnn Wh B-frag table
#define OFF_WGF   103180288    //  32768 bf16 = 65536 B  rnn [ff1|ff2|ta|tb] B-frag table
#define WS_BYTES  103245824

__device__ __forceinline__ unsigned short f2bf(float v) {
    union { float f; unsigned int u; } c; c.f = v;
    unsigned int r = c.u + 0x7FFFu + ((c.u >> 16) & 1u);   // RNE
    return (unsigned short)(r >> 16);
}
__device__ __forceinline__ float bf2f(unsigned short h) {
    union { unsigned int u; float f; } c; c.u = ((unsigned int)h) << 16;
    return c.f;
}
// pack 2 f32 -> 2 bf16 in one dword, RNE, KNOWN-GOOD scalar path (no asm)
__device__ __forceinline__ unsigned int pack2bf(float lo, float hi) {
    return (unsigned int)f2bf(lo) | ((unsigned int)f2bf(hi) << 16);
}

__device__ __forceinline__ float fast_tanh(float x) {
    x = fminf(fmaxf(x, -15.f), 15.f);
    float e = __expf(2.f * x);
    return (e - 1.f) * __builtin_amdgcn_rcpf(e + 1.f);
}
__device__ __forceinline__ float fast_sigmoid(float x) {
    x = fminf(fmaxf(x, -30.f), 30.f);
    return __builtin_amdgcn_rcpf(1.f + __expf(-x));
}

// ---------------- merged weight-prep kernel (5-in-1) ----------------
__global__ __launch_bounds__(256) void prep_all(const float* __restrict__ w1, const float* __restrict__ w2,
                         const float* __restrict__ Wbb,
                         const float* __restrict__ Wff1, const float* __restrict__ Wff2,
                         const float* __restrict__ Wta,  const float* __restrict__ Wtb,
                         unsigned short* __restrict__ w1f, unsigned short* __restrict__ w2f,
                         unsigned short* __restrict__ wbbf,
                         unsigned short* __restrict__ whf, unsigned short* __restrict__ wgf) {
    int bid = blockIdx.x, tid = threadIdx.x;
    if (bid < 6272) {                       // Wbb(feat) -> wbbf, 1605632
        int i = bid * 256 + tid;
        int j = i & 7, lane = (i >> 3) & 63, nt = (i >> 9) & 7, kstep = i >> 12;
        int f = kstep * 32 + (lane >> 4) * 8 + j;
        int col = nt * 16 + (lane & 15);
        wbbf[i] = f2bf(Wbb[(size_t)f * 128 + col]);
    } else if (bid < 6400) {                // w2 -> w2f, 32768
        int i = (bid - 6272) * 256 + tid;
        int j = i & 7, lane = (i >> 3) & 63, kstep = (i >> 9) & 15, nt = i >> 13;
        int oc = nt * 16 + (lane & 15);
        int ic = 2 * kstep + (j >> 2);
        int ky = lane >> 4, kx = j & 3;
        w2f[i] = f2bf(w2[oc * 512 + ic * 16 + ky * 4 + kx]);
    } else if (bid < 6528) {                // gates -> wgf, 32768
        int i = (bid - 6400) * 256 + tid;
        int j = i & 7, lane = (i >> 3) & 63, nt = (i >> 9) & 15, kstep = (i >> 13) & 3;
        int k = kstep * 32 + ((lane >> 4) & 3) * 8 + j;
        int m = nt >> 2;
        int c = (nt & 3) * 16 + (lane & 15);
        const float* Wm = (m == 0) ? Wff1 : (m == 1) ? Wff2 : (m == 2) ? Wta : Wtb;
        wgf[i] = f2bf(Wm[k * 64 + c]);
    } else if (bid < 6560) {                // Wh -> whf, 8192
        int i = (bid - 6528) * 256 + tid;
        int j = i & 7, lane = (i >> 3) & 63, nt = (i >> 9) & 7, kstep = (i >> 12) & 1;
        int k = kstep * 32 + ((lane >> 4) & 3) * 8 + j;
        int col = nt * 16 + (lane & 15);
        whf[i] = f2bf(Wbb[(size_t)(FEATN + k) * 128 + col]);
    } else {                                // w1 -> w1f, 2048
        int i = (bid - 6560) * 256 + tid;
        if (i >= 2048) return;
        int j = i & 7, lane = (i >> 3) & 63, nt = (i >> 9) & 1, kstep = (i >> 10) & 1;
        int oc = nt * 16 + (lane & 15);
        int ky = (lane >> 4) & 3, kx = j & 3;
        float v;
        if (kstep == 0) { int ic = j >> 2; v = w1[oc * 48 + ic * 16 + ky * 4 + kx]; }
        else            { v = (j >> 2) == 0 ? w1[oc * 48 + 32 + ky * 4 + kx] : 0.f; }
        w1f[i] = f2bf(v);
    }
}

// ---------------- fused conv1+conv2, bf16 MFMA, h1 lives only in LDS ----------------
// Part A (conv1): M=900 (57 mtiles), N=32, K=48 (2 ksteps). A-frags built directly
// from global x via float2 loads + f2bf RNE packing (bit-identical to the
// R10-validated staged path). Output to LDS h1s[ic][y][x] (row pitch 32 bf16,
// plane pitch PLANEP dwords). Part B (conv2): validated structure, PLANEP pitch.
__global__ __launch_bounds__(256) void fused_conv(const float* __restrict__ x,
                                                  const float* __restrict__ b1,
                                                  const unsigned short* __restrict__ w1f,
                                                  const float* __restrict__ b2,
                                                  const unsigned short* __restrict__ w2f,
                                                  unsigned short* __restrict__ featb) {
    __shared__ unsigned short h1s[32 * 2 * PLANEP];   // 61696 B
    int img = blockIdx.x;
    int tid = threadIdx.x;
    int lane = tid & 63, wid = tid >> 6;
    int rowl = lane & 15, g = lane >> 4;
    const float* xg = x + (size_t)img * 11532;

    // ---- Part A: conv1 -> h1s ----
    {
        short8 bfr[2][2];
        #pragma unroll
        for (int ks = 0; ks < 2; ++ks)
            #pragma unroll
            for (int nt = 0; nt < 2; ++nt)
                bfr[ks][nt] = *(const short8*)(w1f + (((ks * 2 + nt) * 64 + lane) << 3));
        float bias0 = b1[rowl], bias1 = b1[16 + rowl];

        for (int i = 0; i < 15; ++i) {
            int mtile = wid + 4 * i;
            if (mtile >= 57) break;
            int m = mtile * 16 + rowl; if (m > 899) m = 899;
            int oy = m / 30, ox = m - oy * 30;
            int y = 2 * oy + g, x0 = 2 * ox;
            const float* xb = xg + y * 62 + x0;
            union { unsigned int u[4]; short8 s; } af0, af1;
            #pragma unroll
            for (int c = 0; c < 2; ++c) {
                float2 p0 = *(const float2*)(xb + c * 3844);
                float2 p1 = *(const float2*)(xb + c * 3844 + 2);
                af0.u[c * 2]     = pack2bf(p0.x, p0.y);
                af0.u[c * 2 + 1] = pack2bf(p1.x, p1.y);
            }
            {
                float2 q0 = *(const float2*)(xb + 7688);
                float2 q1 = *(const float2*)(xb + 7690);
                af1.u[0] = pack2bf(q0.x, q0.y);
                af1.u[1] = pack2bf(q1.x, q1.y);
                af1.u[2] = 0; af1.u[3] = 0;
            }
            f32x4 acc0 = (f32x4){0.f, 0.f, 0.f, 0.f};
            f32x4 acc1 = (f32x4){0.f, 0.f, 0.f, 0.f};
            acc0 = __builtin_amdgcn_mfma_f32_16x16x32_bf16(af0.s, bfr[0][0], acc0, 0, 0, 0);
            acc0 = __builtin_amdgcn_mfma_f32_16x16x32_bf16(af1.s, bfr[1][0], acc0, 0, 0, 0);
            acc1 = __builtin_amdgcn_mfma_f32_16x16x32_bf16(af0.s, bfr[0][1], acc1, 0, 0, 0);
            acc1 = __builtin_amdgcn_mfma_f32_16x16x32_bf16(af1.s, bfr[1][1], acc1, 0, 0, 0);
            // epilogue: bias+relu+bf16 -> h1s[oc][oy][ox]
            int sp0 = mtile * 16 + g * 4;
            int oy0 = sp0 / 30, ox0 = sp0 - oy0 * 30;
            #pragma unroll
            for (int nt = 0; nt < 2; ++nt) {
                f32x4 a = nt ? acc1 : acc0;
                int oc = nt * 16 + rowl;
                float bias = nt ? bias1 : bias0;
                int pbase = oc * (2 * PLANEP);
                #pragma unroll
                for (int r = 0; r < 4; ++r) {
                    if (sp0 + r > 899) break;
                    int oxr = ox0 + r, oyr = oy0;
                    if (oxr >= 30) { oxr -= 30; ++oyr; }
                    h1s[pbase + oyr * 32 + oxr] = f2bf(fmaxf(a[r] + bias, 0.f));
                }
            }
        }
    }
    __syncthreads();

    // ---- Part B: conv2 -> featb ----
    f32x4 acc[4][4];
    #pragma unroll
    for (int i = 0; i < 4; ++i)
        #pragma unroll
        for (int nt = 0; nt < 4; ++nt) acc[i][nt] = (f32x4){0.f, 0.f, 0.f, 0.f};

    int dofs[4];
    #pragma unroll
    for (int i = 0; i < 4; ++i) {
        int mtile = wid + 4 * i;
        int m = mtile * 16 + rowl; if (m > 195) m = 195;
        int oy = m / 14, ox = m - oy * 14;
        int y = 2 * oy + g, x0 = 2 * ox;
        dofs[i] = y * 16 + (x0 >> 1);
    }
    const unsigned int* lds32 = (const unsigned int*)h1s;

    #pragma unroll 4
    for (int kstep = 0; kstep < 16; ++kstep) {
        short8 bfr[4];
        #pragma unroll
        for (int nt = 0; nt < 4; ++nt)
            bfr[nt] = *(const short8*)(w2f + (((nt * 16 + kstep) * 64 + lane) << 3));
        int icb = kstep * 2 * PLANEP;
        #pragma unroll
        for (int i = 0; i < 4; ++i) {
            int mtile = wid + 4 * i;
            if (mtile < 13) {
                int dof = icb + dofs[i];
                union { unsigned int u[4]; short8 s; } af;
                af.u[0] = lds32[dof];
                af.u[1] = lds32[dof + 1];
                af.u[2] = lds32[dof + PLANEP];
                af.u[3] = lds32[dof + PLANEP + 1];
                #pragma unroll
                for (int nt = 0; nt < 4; ++nt)
                    acc[i][nt] = __builtin_amdgcn_mfma_f32_16x16x32_bf16(af.s, bfr[nt], acc[i][nt], 0, 0, 0);
            }
        }
    }
    #pragma unroll
    for (int i = 0; i < 4; ++i) {
        int mtile = wid + 4 * i;
        if (mtile >= 13) continue;
        int sp0 = mtile * 16 + g * 4;
        #pragma unroll
        for (int nt = 0; nt < 4; ++nt) {
            int oc = nt * 16 + rowl;
            float bias = b2[oc];
            unsigned short pk[4];
            #pragma unroll
            for (int r = 0; r < 4; ++r)
                pk[r] = f2bf(fmaxf(acc[i][nt][r] + bias, 0.f));
            unsigned short* dstp = featb + (size_t)img * 12544 + oc * 196 + sp0;
            if (sp0 + 3 < 196) {
                *(uint2*)dstp = *(uint2*)pk;
            } else {
                #pragma unroll
                for (int r = 0; r < 4; ++r) if (sp0 + r < 196) dstp[r] = pk[r];
            }
        }
    }
}

// ---------------- u = feat @ W_in : bf16 MFMA, split-K=28 ----------------
__global__ __launch_bounds__(256) void gemm_u_mfma(const unsigned short* __restrict__ featb,
                                                   const unsigned short* __restrict__ Wbbf,
                                                   float* __restrict__ part) {
    int tid = threadIdx.x, lane = tid & 63, wid = tid >> 6;
    int rowl = lane & 15, g = lane >> 4;
    int m0 = blockIdx.x * 64 + wid * 16;
    int ks0 = blockIdx.y * 14;
    f32x4 acc[8];
    #pragma unroll
    for (int nt = 0; nt < 8; ++nt) acc[nt] = (f32x4){0.f, 0.f, 0.f, 0.f};
    const unsigned short* arow = featb + (size_t)(m0 + rowl) * FEATN + g * 8;
    #pragma unroll 2
    for (int kk = 0; kk < 14; ++kk) {
        int kstep = ks0 + kk;
        short8 afr = *(const short8*)(arow + kstep * 32);
        #pragma unroll
        for (int nt = 0; nt < 8; ++nt) {
            short8 bfr = *(const short8*)(Wbbf + ((((size_t)kstep * 8 + nt) * 64 + lane) << 3));
            acc[nt] = __builtin_amdgcn_mfma_f32_16x16x32_bf16(afr, bfr, acc[nt], 0, 0, 0);
        }
    }
    float* pg = part + (size_t)blockIdx.y * 131072;
    #pragma unroll
    for (int nt = 0; nt < 8; ++nt)
        #pragma unroll
        for (int r = 0; r < 4; ++r)
            pg[(m0 + g * 4 + r) * 128 + nt * 16 + rowl] = acc[nt][r];
}

// reduce into u laid out [t][b][128]
__global__ void reduce_u(const float* __restrict__ part, const float* __restrict__ bbb,
                         float* __restrict__ u) {
    int o = blockIdx.x * 256 + threadIdx.x;   // 131072 total
    int c = o & 127, b = (o >> 7) & 15, t = o >> 11;
    int m = b * 64 + t;
    float s = bbb[c];
    #pragma unroll
    for (int ks = 0; ks < 28; ++ks) s += part[(size_t)ks * 131072 + m * 128 + c];
    u[o] = s;
}

// ---------------- liquid RNN scan: batched MFMA (M=16 batches), 1 block, 4 waves ----------------
// R7-measured structure (90 us): plain __syncthreads, separate hi/lo LDS arrays,
// depth-1 u register prefetch, XOR-swizzled LDS (same involution both sides).
__global__ __launch_bounds__(256, 1) void rnn_mfma(const float* __restrict__ u,
                                                   const unsigned short* __restrict__ whf,
                                                   const unsigned short* __restrict__ wgf,
                                                   const float* __restrict__ bff1,
                                                   const float* __restrict__ bff2,
                                                   const float* __restrict__ bta,
                                                   const float* __restrict__ btb,
                                                   float* __restrict__ hid_out) {
    __shared__ unsigned short hidA_hi[16 * 64], hidA_lo[16 * 64];   // [row][k0..63]
    __shared__ unsigned short zA_hi[16 * 128], zA_lo[16 * 128];     // [row][k0..127]
    int tid = threadIdx.x, lane = tid & 63, w = tid >> 6;
    int rowl = lane & 15, g = lane >> 4;

    for (int idx = tid; idx < 1024; idx += 256) { hidA_hi[idx] = 0; hidA_lo[idx] = 0; }

    // B-fragments -> registers (once)
    short8 wh_r[2][2];   // [kstep][ntl], nt_abs = 2w + ntl
    #pragma unroll
    for (int ks = 0; ks < 2; ++ks)
        #pragma unroll
        for (int ntl = 0; ntl < 2; ++ntl)
            wh_r[ks][ntl] = *(const short8*)(whf + (((ks * 8 + 2 * w + ntl) * 64 + lane) << 3));
    short8 wg_r[4][4];   // [m][kstep], nt_abs = 4m + w
    #pragma unroll
    for (int m = 0; m < 4; ++m)
        #pragma unroll
        for (int ks = 0; ks < 4; ++ks)
            wg_r[m][ks] = *(const short8*)(wgf + (((ks * 16 + 4 * m + w) * 64 + lane) << 3));

    int cc = w * 16 + rowl;                   // this lane's phase-2 column
    float bias1 = bff1[cc], bias2 = bff2[cc], biast = bta[cc] + btb[cc];

    // u prefetch (t=0)
    float upf[8];
    #pragma unroll
    for (int i = 0; i < 8; ++i) {
        int ntl = i >> 2, r = i & 3;
        upf[i] = u[(g * 4 + r) * 128 + (2 * w + ntl) * 16 + rowl];
    }
    __syncthreads();

    float hidv[4];
    #pragma unroll 1
    for (int t = 0; t < 64; ++t) {
        // ---- Phase 1 ----
        short8 ah[2], al[2];
        #pragma unroll
        for (int ks = 0; ks < 2; ++ks) {
            int byte = (rowl * 128 + ks * 64 + g * 16) ^ ((rowl & 7) << 4);
            ah[ks] = *(const short8*)((const char*)hidA_hi + byte);
            al[ks] = *(const short8*)((const char*)hidA_lo + byte);
        }
        f32x4 zacc[2];
        #pragma unroll
        for (int ntl = 0; ntl < 2; ++ntl) {
            zacc[ntl] = (f32x4){upf[ntl * 4 + 0], upf[ntl * 4 + 1], upf[ntl * 4 + 2], upf[ntl * 4 + 3]};
            #pragma unroll
            for (int ks = 0; ks < 2; ++ks) {
                zacc[ntl] = __builtin_amdgcn_mfma_f32_16x16x32_bf16(al[ks], wh_r[ks][ntl], zacc[ntl], 0, 0, 0);
                zacc[ntl] = __builtin_amdgcn_mfma_f32_16x16x32_bf16(ah[ks], wh_r[ks][ntl], zacc[ntl], 0, 0, 0);
            }
        }
        // prefetch u for t+1 (overlaps rest of step)
        if (t < 63) {
            #pragma unroll
            for (int i = 0; i < 8; ++i) {
                int ntl = i >> 2, r = i & 3;
                upf[i] = u[(t + 1) * 2048 + (g * 4 + r) * 128 + (2 * w + ntl) * 16 + rowl];
            }
        }
        // tanh + write z (hi/lo) to LDS
        #pragma unroll
        for (int ntl = 0; ntl < 2; ++ntl)
            #pragma unroll
            for (int r = 0; r < 4; ++r) {
                float zv = 1.7159f * fast_tanh(0.666f * zacc[ntl][r]);
                int row = g * 4 + r, c = w * 32 + ntl * 16 + rowl;
                unsigned short zh = f2bf(zv);
                unsigned short zl = f2bf(zv - bf2f(zh));
                int byte = (row * 256 + c * 2) ^ ((row & 7) << 4);
                *(unsigned short*)((char*)zA_hi + byte) = zh;
                *(unsigned short*)((char*)zA_lo + byte) = zl;
            }
        __syncthreads();
        // ---- Phase 2 ----
        short8 zh[4], zl[4];
        #pragma unroll
        for (int ks = 0; ks < 4; ++ks) {
            int byte = (rowl * 256 + ks * 64 + g * 16) ^ ((rowl & 7) << 4);
            zh[ks] = *(const short8*)((const char*)zA_hi + byte);
            zl[ks] = *(const short8*)((const char*)zA_lo + byte);
        }
        f32x4 facc[4];
        facc[0] = (f32x4){bias1, bias1, bias1, bias1};
        facc[1] = (f32x4){bias2, bias2, bias2, bias2};
        facc[2] = (f32x4){biast, biast, biast, biast};
        facc[3] = (f32x4){0.f, 0.f, 0.f, 0.f};
        #pragma unroll
        for (int m = 0; m < 4; ++m)
            #pragma unroll
            for (int ks = 0; ks < 4; ++ks) {
                facc[m] = __builtin_amdgcn_mfma_f32_16x16x32_bf16(zl[ks], wg_r[m][ks], facc[m], 0, 0, 0);
                facc[m] = __builtin_amdgcn_mfma_f32_16x16x32_bf16(zh[ks], wg_r[m][ks], facc[m], 0, 0, 0);
            }
        // activations + hid (hi/lo) write
        #pragma unroll
        for (int r = 0; r < 4; ++r) {
            float ff1 = fast_tanh(facc[0][r]);
            float ff2 = fast_tanh(facc[1][r]);
            float tt  = fast_sigmoid(facc[2][r] + facc[3][r]);
            float hv  = ff1 * (1.f - tt) + tt * ff2;
            hidv[r] = hv;
            int row = g * 4 + r;
            unsigned short hh = f2bf(hv);
            unsigned short hl = f2bf(hv - bf2f(hh));
            int byte = (row * 128 + cc * 2) ^ ((row & 7) << 4);
            *(unsigned short*)((char*)hidA_hi + byte) = hh;
            *(unsigned short*)((char*)hidA_lo + byte) = hl;
        }
        __syncthreads();
    }
    #pragma unroll
    for (int r = 0; r < 4; ++r)
        hid_out[(g * 4 + r) * 64 + cc] = hidv[r];
}

// ---------------- head ----------------
__global__ void head_kernel(const float* __restrict__ hid, const float* __restrict__ Wout,
                            const float* __restrict__ bout, float* __restrict__ out) {
    int tid = threadIdx.x;           // 128 = 16*8
    int b = tid >> 3, a = tid & 7;
    float s = bout[a];
    #pragma unroll
    for (int j = 0; j < 64; ++j) s += hid[b * 64 + j] * Wout[j * 8 + a];
    out[tid] = s;
}

extern "C" void kernel_launch(void* const* d_in, const int* in_sizes, int n_in,
                              void* d_out, int out_size, void* d_ws, size_t ws_size,
                              hipStream_t stream) {
    const float* x    = (const float*)d_in[0];
    const float* w1   = (const float*)d_in[1];
    const float* b1   = (const float*)d_in[2];
    const float* w2   = (const float*)d_in[3];
    const float* b2   = (const float*)d_in[4];
    const float* Wbb  = (const float*)d_in[5];
    const float* bbb  = (const float*)d_in[6];
    const float* Wff1 = (const float*)d_in[7];
    const float* bff1 = (const float*)d_in[8];
    const float* Wff2 = (const float*)d_in[9];
    const float* bff2 = (const float*)d_in[10];
    const float* Wta  = (const float*)d_in[11];
    const float* bta  = (const float*)d_in[12];
    const float* Wtb  = (const float*)d_in[13];
    const float* btb  = (const float*)d_in[14];
    const float* Wout = (const float*)d_in[15];
    const float* bout = (const float*)d_in[16];

    if (ws_size < (size_t)WS_BYTES) return;

    char* wsb = (char*)d_ws;
    unsigned short* w1f   = (unsigned short*)(wsb + OFF_W1F);
    unsigned short* w2f   = (unsigned short*)(wsb + OFF_W2F);
    unsigned short* wbbf  = (unsigned short*)(wsb + OFF_WBBF);
    unsigned short* featb = (unsigned short*)(wsb + OFF_FEATB);
    float*          u     = (float*)(wsb + OFF_U);
    float*          part  = (float*)(wsb + OFF_PART);
    float*          hid   = (float*)(wsb + OFF_HID);
    unsigned short* whf   = (unsigned short*)(wsb + OFF_WHF);
    unsigned short* wgf   = (unsigned short*)(wsb + OFF_WGF);

    prep_all<<<6568, 256, 0, stream>>>(w1, w2, Wbb, Wff1, Wff2, Wta, Wtb,
                                       w1f, w2f, wbbf, whf, wgf);
    fused_conv<<<1024, 256, 0, stream>>>(x, b1, w1f, b2, w2f, featb);
    gemm_u_mfma<<<dim3(16, 28), 256, 0, stream>>>(featb, wbbf, part);
    reduce_u<<<512, 256, 0, stream>>>(part, bbb, u);
    rnn_mfma<<<1, 256, 0, stream>>>(u, whf, wgf, bff1, bff2, bta, btb, hid);
    head_kernel<<<1, 128, 0, stream>>>(hid, Wout, bout, (float*)d_out);
}

// Round 13
// 144.172 us; speedup vs baseline: 1.7474x; 1.1204x over previous
//
#include <hip/hip_runtime.h>
#include <hip/hip_bf16.h>
#include <math.h>

#define FEATN 12544
#define NIMG 1024
#define PLANEP 482   // h1s per-ic plane pitch in dwords (482%32=2 -> spreads banks)

typedef __attribute__((ext_vector_type(8))) short short8;
typedef __attribute__((ext_vector_type(4))) float f32x4;

// ---- ws byte offsets (all sizes in BYTES; bf16 regions are 2 B/elem) ----
#define OFF_W1F   0            //  2048 bf16  =     4096 B   conv1 B-frag table
#define OFF_W2F   6144         //  32768 bf16 =    65536 B   conv2 B-frag table
#define OFF_WBBF  71680        //  1605632 bf16 = 3211264 B  gemm_u B-frag table
#define OFF_FEATB 62265344     //  1024*12544 bf16 = 25690112 B
#define OFF_U     87955456     //  131072 f32 = 524288 B   (layout [t][b][128])
#define OFF_PART  88479744     //  28*131072 f32 = 14680064 B
#define OFF_HID   103159808    //  1024 f32 = 4096 B
#define OFF_WHF   103163904    //  8192 bf16 = 16384 B   rnn Wh B-frag table
#define OFF_WGF   103180288    //  32768 bf16 = 65536 B  rnn [ff1|ff2|ta|tb] B-frag table
#define WS_BYTES  103245824

__device__ __forceinline__ unsigned short f2bf(float v) {
    union { float f; unsigned int u; } c; c.f = v;
    unsigned int r = c.u + 0x7FFFu + ((c.u >> 16) & 1u);   // RNE
    return (unsigned short)(r >> 16);
}
__device__ __forceinline__ float bf2f(unsigned short h) {
    union { unsigned int u; float f; } c; c.u = ((unsigned int)h) << 16;
    return c.f;
}
// pack 2 f32 -> 2 bf16 in one dword, RNE, KNOWN-GOOD scalar path (no asm)
__device__ __forceinline__ unsigned int pack2bf(float lo, float hi) {
    return (unsigned int)f2bf(lo) | ((unsigned int)f2bf(hi) << 16);
}

__device__ __forceinline__ float fast_tanh(float x) {
    x = fminf(fmaxf(x, -15.f), 15.f);
    float e = __expf(2.f * x);
    return (e - 1.f) * __builtin_amdgcn_rcpf(e + 1.f);
}
__device__ __forceinline__ float fast_sigmoid(float x) {
    x = fminf(fmaxf(x, -30.f), 30.f);
    return __builtin_amdgcn_rcpf(1.f + __expf(-x));
}

// ---------------- merged weight-prep kernel (5-in-1) ----------------
__global__ __launch_bounds__(256) void prep_all(const float* __restrict__ w1, const float* __restrict__ w2,
                         const float* __restrict__ Wbb,
                         const float* __restrict__ Wff1, const float* __restrict__ Wff2,
                         const float* __restrict__ Wta,  const float* __restrict__ Wtb,
                         unsigned short* __restrict__ w1f, unsigned short* __restrict__ w2f,
                         unsigned short* __restrict__ wbbf,
                         unsigned short* __restrict__ whf, unsigned short* __restrict__ wgf) {
    int bid = blockIdx.x, tid = threadIdx.x;
    if (bid < 6272) {                       // Wbb(feat) -> wbbf, 1605632
        int i = bid * 256 + tid;
        int j = i & 7, lane = (i >> 3) & 63, nt = (i >> 9) & 7, kstep = i >> 12;
        int f = kstep * 32 + (lane >> 4) * 8 + j;
        int col = nt * 16 + (lane & 15);
        wbbf[i] = f2bf(Wbb[(size_t)f * 128 + col]);
    } else if (bid < 6400) {                // w2 -> w2f, 32768
        int i = (bid - 6272) * 256 + tid;
        int j = i & 7, lane = (i >> 3) & 63, kstep = (i >> 9) & 15, nt = i >> 13;
        int oc = nt * 16 + (lane & 15);
        int ic = 2 * kstep + (j >> 2);
        int ky = lane >> 4, kx = j & 3;
        w2f[i] = f2bf(w2[oc * 512 + ic * 16 + ky * 4 + kx]);
    } else if (bid < 6528) {                // gates -> wgf, 32768
        int i = (bid - 6400) * 256 + tid;
        int j = i & 7, lane = (i >> 3) & 63, nt = (i >> 9) & 15, kstep = (i >> 13) & 3;
        int k = kstep * 32 + ((lane >> 4) & 3) * 8 + j;
        int m = nt >> 2;
        int c = (nt & 3) * 16 + (lane & 15);
        const float* Wm = (m == 0) ? Wff1 : (m == 1) ? Wff2 : (m == 2) ? Wta : Wtb;
        wgf[i] = f2bf(Wm[k * 64 + c]);
    } else if (bid < 6560) {                // Wh -> whf, 8192
        int i = (bid - 6528) * 256 + tid;
        int j = i & 7, lane = (i >> 3) & 63, nt = (i >> 9) & 7, kstep = (i >> 12) & 1;
        int k = kstep * 32 + ((lane >> 4) & 3) * 8 + j;
        int col = nt * 16 + (lane & 15);
        whf[i] = f2bf(Wbb[(size_t)(FEATN + k) * 128 + col]);
    } else {                                // w1 -> w1f, 2048
        int i = (bid - 6560) * 256 + tid;
        if (i >= 2048) return;
        int j = i & 7, lane = (i >> 3) & 63, nt = (i >> 9) & 1, kstep = (i >> 10) & 1;
        int oc = nt * 16 + (lane & 15);
        int ky = (lane >> 4) & 3, kx = j & 3;
        float v;
        if (kstep == 0) { int ic = j >> 2; v = w1[oc * 48 + ic * 16 + ky * 4 + kx]; }
        else            { v = (j >> 2) == 0 ? w1[oc * 48 + 32 + ky * 4 + kx] : 0.f; }
        w1f[i] = f2bf(v);
    }
}

// ---------------- fused conv1+conv2, bf16 MFMA, h1 lives only in LDS ----------------
__global__ __launch_bounds__(256) void fused_conv(const float* __restrict__ x,
                                                  const float* __restrict__ b1,
                                                  const unsigned short* __restrict__ w1f,
                                                  const float* __restrict__ b2,
                                                  const unsigned short* __restrict__ w2f,
                                                  unsigned short* __restrict__ featb) {
    __shared__ unsigned short h1s[32 * 2 * PLANEP];   // 61696 B
    int img = blockIdx.x;
    int tid = threadIdx.x;
    int lane = tid & 63, wid = tid >> 6;
    int rowl = lane & 15, g = lane >> 4;
    const float* xg = x + (size_t)img * 11532;

    // ---- Part A: conv1 -> h1s ----
    {
        short8 bfr[2][2];
        #pragma unroll
        for (int ks = 0; ks < 2; ++ks)
            #pragma unroll
            for (int nt = 0; nt < 2; ++nt)
                bfr[ks][nt] = *(const short8*)(w1f + (((ks * 2 + nt) * 64 + lane) << 3));
        float bias0 = b1[rowl], bias1 = b1[16 + rowl];

        for (int i = 0; i < 15; ++i) {
            int mtile = wid + 4 * i;
            if (mtile >= 57) break;
            int m = mtile * 16 + rowl; if (m > 899) m = 899;
            int oy = m / 30, ox = m - oy * 30;
            int y = 2 * oy + g, x0 = 2 * ox;
            const float* xb = xg + y * 62 + x0;
            union { unsigned int u[4]; short8 s; } af0, af1;
            #pragma unroll
            for (int c = 0; c < 2; ++c) {
                float2 p0 = *(const float2*)(xb + c * 3844);
                float2 p1 = *(const float2*)(xb + c * 3844 + 2);
                af0.u[c * 2]     = pack2bf(p0.x, p0.y);
                af0.u[c * 2 + 1] = pack2bf(p1.x, p1.y);
            }
            {
                float2 q0 = *(const float2*)(xb + 7688);
                float2 q1 = *(const float2*)(xb + 7690);
                af1.u[0] = pack2bf(q0.x, q0.y);
                af1.u[1] = pack2bf(q1.x, q1.y);
                af1.u[2] = 0; af1.u[3] = 0;
            }
            f32x4 acc0 = (f32x4){0.f, 0.f, 0.f, 0.f};
            f32x4 acc1 = (f32x4){0.f, 0.f, 0.f, 0.f};
            acc0 = __builtin_amdgcn_mfma_f32_16x16x32_bf16(af0.s, bfr[0][0], acc0, 0, 0, 0);
            acc0 = __builtin_amdgcn_mfma_f32_16x16x32_bf16(af1.s, bfr[1][0], acc0, 0, 0, 0);
            acc1 = __builtin_amdgcn_mfma_f32_16x16x32_bf16(af0.s, bfr[0][1], acc1, 0, 0, 0);
            acc1 = __builtin_amdgcn_mfma_f32_16x16x32_bf16(af1.s, bfr[1][1], acc1, 0, 0, 0);
            // epilogue: bias+relu+bf16 -> h1s[oc][oy][ox]
            int sp0 = mtile * 16 + g * 4;
            int oy0 = sp0 / 30, ox0 = sp0 - oy0 * 30;
            #pragma unroll
            for (int nt = 0; nt < 2; ++nt) {
                f32x4 a = nt ? acc1 : acc0;
                int oc = nt * 16 + rowl;
                float bias = nt ? bias1 : bias0;
                int pbase = oc * (2 * PLANEP);
                #pragma unroll
                for (int r = 0; r < 4; ++r) {
                    if (sp0 + r > 899) break;
                    int oxr = ox0 + r, oyr = oy0;
                    if (oxr >= 30) { oxr -= 30; ++oyr; }
                    h1s[pbase + oyr * 32 + oxr] = f2bf(fmaxf(a[r] + bias, 0.f));
                }
            }
        }
    }
    __syncthreads();

    // ---- Part B: conv2 -> featb ----
    f32x4 acc[4][4];
    #pragma unroll
    for (int i = 0; i < 4; ++i)
        #pragma unroll
        for (int nt = 0; nt < 4; ++nt) acc[i][nt] = (f32x4){0.f, 0.f, 0.f, 0.f};

    int dofs[4];
    #pragma unroll
    for (int i = 0; i < 4; ++i) {
        int mtile = wid + 4 * i;
        int m = mtile * 16 + rowl; if (m > 195) m = 195;
        int oy = m / 14, ox = m - oy * 14;
        int y = 2 * oy + g, x0 = 2 * ox;
        dofs[i] = y * 16 + (x0 >> 1);
    }
    const unsigned int* lds32 = (const unsigned int*)h1s;

    #pragma unroll 4
    for (int kstep = 0; kstep < 16; ++kstep) {
        short8 bfr[4];
        #pragma unroll
        for (int nt = 0; nt < 4; ++nt)
            bfr[nt] = *(const short8*)(w2f + (((nt * 16 + kstep) * 64 + lane) << 3));
        int icb = kstep * 2 * PLANEP;
        #pragma unroll
        for (int i = 0; i < 4; ++i) {
            int mtile = wid + 4 * i;
            if (mtile < 13) {
                int dof = icb + dofs[i];
                union { unsigned int u[4]; short8 s; } af;
                af.u[0] = lds32[dof];
                af.u[1] = lds32[dof + 1];
                af.u[2] = lds32[dof + PLANEP];
                af.u[3] = lds32[dof + PLANEP + 1];
                #pragma unroll
                for (int nt = 0; nt < 4; ++nt)
                    acc[i][nt] = __builtin_amdgcn_mfma_f32_16x16x32_bf16(af.s, bfr[nt], acc[i][nt], 0, 0, 0);
            }
        }
    }
    #pragma unroll
    for (int i = 0; i < 4; ++i) {
        int mtile = wid + 4 * i;
        if (mtile >= 13) continue;
        int sp0 = mtile * 16 + g * 4;
        #pragma unroll
        for (int nt = 0; nt < 4; ++nt) {
            int oc = nt * 16 + rowl;
            float bias = b2[oc];
            unsigned short pk[4];
            #pragma unroll
            for (int r = 0; r < 4; ++r)
                pk[r] = f2bf(fmaxf(acc[i][nt][r] + bias, 0.f));
            unsigned short* dstp = featb + (size_t)img * 12544 + oc * 196 + sp0;
            if (sp0 + 3 < 196) {
                *(uint2*)dstp = *(uint2*)pk;
            } else {
                #pragma unroll
                for (int r = 0; r < 4; ++r) if (sp0 + r < 196) dstp[r] = pk[r];
            }
        }
    }
}

// ---------------- u = feat @ W_in : bf16 MFMA, split-K=28 ----------------
__global__ __launch_bounds__(256) void gemm_u_mfma(const unsigned short* __restrict__ featb,
                                                   const unsigned short* __restrict__ Wbbf,
                                                   float* __restrict__ part) {
    int tid = threadIdx.x, lane = tid & 63, wid = tid >> 6;
    int rowl = lane & 15, g = lane >> 4;
    int m0 = blockIdx.x * 64 + wid * 16;
    int ks0 = blockIdx.y * 14;
    f32x4 acc[8];
    #pragma unroll
    for (int nt = 0; nt < 8; ++nt) acc[nt] = (f32x4){0.f, 0.f, 0.f, 0.f};
    const unsigned short* arow = featb + (size_t)(m0 + rowl) * FEATN + g * 8;
    #pragma unroll 2
    for (int kk = 0; kk < 14; ++kk) {
        int kstep = ks0 + kk;
        short8 afr = *(const short8*)(arow + kstep * 32);
        #pragma unroll
        for (int nt = 0; nt < 8; ++nt) {
            short8 bfr = *(const short8*)(Wbbf + ((((size_t)kstep * 8 + nt) * 64 + lane) << 3));
            acc[nt] = __builtin_amdgcn_mfma_f32_16x16x32_bf16(afr, bfr, acc[nt], 0, 0, 0);
        }
    }
    float* pg = part + (size_t)blockIdx.y * 131072;
    #pragma unroll
    for (int nt = 0; nt < 8; ++nt)
        #pragma unroll
        for (int r = 0; r < 4; ++r)
            pg[(m0 + g * 4 + r) * 128 + nt * 16 + rowl] = acc[nt][r];
}

// reduce into u laid out [t][b][128]
__global__ void reduce_u(const float* __restrict__ part, const float* __restrict__ bbb,
                         float* __restrict__ u) {
    int o = blockIdx.x * 256 + threadIdx.x;   // 131072 total
    int c = o & 127, b = (o >> 7) & 15, t = o >> 11;
    int m = b * 64 + t;
    float s = bbb[c];
    #pragma unroll
    for (int ks = 0; ks < 28; ++ks) s += part[(size_t)ks * 131072 + m * 128 + c];
    u[o] = s;
}

// ---------------- liquid RNN scan: batched MFMA, 1 block, 4 waves, single-bf16 state ----------------
// R7 structure with the hi/lo split dropped: z/hid stored as plain bf16 (RNE).
// Halves LDS traffic (72 instrs/step/CU) and MFMA count (20/wave/step).
// XOR-swizzle identical on write and read (same involution both sides).
__global__ __launch_bounds__(256, 1) void rnn_mfma(const float* __restrict__ u,
                                                   const unsigned short* __restrict__ whf,
                                                   const unsigned short* __restrict__ wgf,
                                                   const float* __restrict__ bff1,
                                                   const float* __restrict__ bff2,
                                                   const float* __restrict__ bta,
                                                   const float* __restrict__ btb,
                                                   float* __restrict__ hid_out) {
    __shared__ unsigned short hidA[16 * 64];    // [row][k0..63]
    __shared__ unsigned short zA[16 * 128];     // [row][k0..127]
    int tid = threadIdx.x, lane = tid & 63, w = tid >> 6;
    int rowl = lane & 15, g = lane >> 4;

    for (int idx = tid; idx < 1024; idx += 256) hidA[idx] = 0;

    // B-fragments -> registers (once)
    short8 wh_r[2][2];   // [kstep][ntl], nt_abs = 2w + ntl
    #pragma unroll
    for (int ks = 0; ks < 2; ++ks)
        #pragma unroll
        for (int ntl = 0; ntl < 2; ++ntl)
            wh_r[ks][ntl] = *(const short8*)(whf + (((ks * 8 + 2 * w + ntl) * 64 + lane) << 3));
    short8 wg_r[4][4];   // [m][kstep], nt_abs = 4m + w
    #pragma unroll
    for (int m = 0; m < 4; ++m)
        #pragma unroll
        for (int ks = 0; ks < 4; ++ks)
            wg_r[m][ks] = *(const short8*)(wgf + (((ks * 16 + 4 * m + w) * 64 + lane) << 3));

    int cc = w * 16 + rowl;                   // this lane's phase-2 column
    float bias1 = bff1[cc], bias2 = bff2[cc], biast = bta[cc] + btb[cc];

    // u prefetch (t=0)
    float upf[8];
    #pragma unroll
    for (int i = 0; i < 8; ++i) {
        int ntl = i >> 2, r = i & 3;
        upf[i] = u[(g * 4 + r) * 128 + (2 * w + ntl) * 16 + rowl];
    }
    __syncthreads();

    float hidv[4];
    #pragma unroll 1
    for (int t = 0; t < 64; ++t) {
        // ---- Phase 1: z = lecun_tanh(u_t + hid @ Wh) ----
        short8 ah[2];
        #pragma unroll
        for (int ks = 0; ks < 2; ++ks) {
            int byte = (rowl * 128 + ks * 64 + g * 16) ^ ((rowl & 7) << 4);
            ah[ks] = *(const short8*)((const char*)hidA + byte);
        }
        f32x4 zacc[2];
        #pragma unroll
        for (int ntl = 0; ntl < 2; ++ntl) {
            zacc[ntl] = (f32x4){upf[ntl * 4 + 0], upf[ntl * 4 + 1], upf[ntl * 4 + 2], upf[ntl * 4 + 3]};
            #pragma unroll
            for (int ks = 0; ks < 2; ++ks)
                zacc[ntl] = __builtin_amdgcn_mfma_f32_16x16x32_bf16(ah[ks], wh_r[ks][ntl], zacc[ntl], 0, 0, 0);
        }
        // prefetch u for t+1 (overlaps rest of step)
        if (t < 63) {
            #pragma unroll
            for (int i = 0; i < 8; ++i) {
                int ntl = i >> 2, r = i & 3;
                upf[i] = u[(t + 1) * 2048 + (g * 4 + r) * 128 + (2 * w + ntl) * 16 + rowl];
            }
        }
        // tanh + write z (bf16) to LDS
        #pragma unroll
        for (int ntl = 0; ntl < 2; ++ntl)
            #pragma unroll
            for (int r = 0; r < 4; ++r) {
                float zv = 1.7159f * fast_tanh(0.666f * zacc[ntl][r]);
                int row = g * 4 + r, c = w * 32 + ntl * 16 + rowl;
                int byte = (row * 256 + c * 2) ^ ((row & 7) << 4);
                *(unsigned short*)((char*)zA + byte) = f2bf(zv);
            }
        __syncthreads();
        // ---- Phase 2: [ff1|ff2|ta|tb] = z @ Wg ----
        short8 zfr[4];
        #pragma unroll
        for (int ks = 0; ks < 4; ++ks) {
            int byte = (rowl * 256 + ks * 64 + g * 16) ^ ((rowl & 7) << 4);
            zfr[ks] = *(const short8*)((const char*)zA + byte);
        }
        f32x4 facc[4];
        facc[0] = (f32x4){bias1, bias1, bias1, bias1};
        facc[1] = (f32x4){bias2, bias2, bias2, bias2};
        facc[2] = (f32x4){biast, biast, biast, biast};
        facc[3] = (f32x4){0.f, 0.f, 0.f, 0.f};
        #pragma unroll
        for (int m = 0; m < 4; ++m)
            #pragma unroll
            for (int ks = 0; ks < 4; ++ks)
                facc[m] = __builtin_amdgcn_mfma_f32_16x16x32_bf16(zfr[ks], wg_r[m][ks], facc[m], 0, 0, 0);
        // activations + hid write (bf16)
        #pragma unroll
        for (int r = 0; r < 4; ++r) {
            float ff1 = fast_tanh(facc[0][r]);
            float ff2 = fast_tanh(facc[1][r]);
            float tt  = fast_sigmoid(facc[2][r] + facc[3][r]);
            float hv  = ff1 * (1.f - tt) + tt * ff2;
            hidv[r] = hv;
            int row = g * 4 + r;
            int byte = (row * 128 + cc * 2) ^ ((row & 7) << 4);
            *(unsigned short*)((char*)hidA + byte) = f2bf(hv);
        }
        __syncthreads();
    }
    #pragma unroll
    for (int r = 0; r < 4; ++r)
        hid_out[(g * 4 + r) * 64 + cc] = hidv[r];
}

// ---------------- head ----------------
__global__ void head_kernel(const float* __restrict__ hid, const float* __restrict__ Wout,
                            const float* __restrict__ bout, float* __restrict__ out) {
    int tid = threadIdx.x;           // 128 = 16*8
    int b = tid >> 3, a = tid & 7;
    float s = bout[a];
    #pragma unroll
    for (int j = 0; j < 64; ++j) s += hid[b * 64 + j] * Wout[j * 8 + a];
    out[tid] = s;
}

extern "C" void kernel_launch(void* const* d_in, const int* in_sizes, int n_in,
                              void* d_out, int out_size, void* d_ws, size_t ws_size,
                              hipStream_t stream) {
    const float* x    = (const float*)d_in[0];
    const float* w1   = (const float*)d_in[1];
    const float* b1   = (const float*)d_in[2];
    const float* w2   = (const float*)d_in[3];
    const float* b2   = (const float*)d_in[4];
    const float* Wbb  = (const float*)d_in[5];
    const float* bbb  = (const float*)d_in[6];
    const float* Wff1 = (const float*)d_in[7];
    const float* bff1 = (const float*)d_in[8];
    const float* Wff2 = (const float*)d_in[9];
    const float* bff2 = (const float*)d_in[10];
    const float* Wta  = (const float*)d_in[11];
    const float* bta  = (const float*)d_in[12];
    const float* Wtb  = (const float*)d_in[13];
    const float* btb  = (const float*)d_in[14];
    const float* Wout = (const float*)d_in[15];
    const float* bout = (const float*)d_in[16];

    if (ws_size < (size_t)WS_BYTES) return;

    char* wsb = (char*)d_ws;
    unsigned short* w1f   = (unsigned short*)(wsb + OFF_W1F);
    unsigned short* w2f   = (unsigned short*)(wsb + OFF_W2F);
    unsigned short* wbbf  = (unsigned short*)(wsb + OFF_WBBF);
    unsigned short* featb = (unsigned short*)(wsb + OFF_FEATB);
    float*          u     = (float*)(wsb + OFF_U);
    float*          part  = (float*)(wsb + OFF_PART);
    float*          hid   = (float*)(wsb + OFF_HID);
    unsigned short* whf   = (unsigned short*)(wsb + OFF_WHF);
    unsigned short* wgf   = (unsigned short*)(wsb + OFF_WGF);

    prep_all<<<6568, 256, 0, stream>>>(w1, w2, Wbb, Wff1, Wff2, Wta, Wtb,
                                       w1f, w2f, wbbf, whf, wgf);
    fused_conv<<<1024, 256, 0, stream>>>(x, b1, w1f, b2, w2f, featb);
    gemm_u_mfma<<<dim3(16, 28), 256, 0, stream>>>(featb, wbbf, part);
    reduce_u<<<512, 256, 0, stream>>>(part, bbb, u);
    rnn_mfma<<<1, 256, 0, stream>>>(u, whf, wgf, bff1, bff2, bta, btb, hid);
    head_kernel<<<1, 128, 0, stream>>>(hid, Wout, bout, (float*)d_out);
}

// Round 14
// 130.108 us; speedup vs baseline: 1.9363x; 1.1081x over previous
//
#include <hip/hip_runtime.h>
#include <hip/hip_bf16.h>
#include <math.h>

#define FEATN 12544
#define NIMG 1024
#define PLANEP 482   // h1s per-ic plane pitch in dwords (482%32=2 -> spreads banks)

typedef __attribute__((ext_vector_type(8))) short short8;
typedef __attribute__((ext_vector_type(4))) float f32x4;

// ---- ws byte offsets (all sizes in BYTES; bf16 regions are 2 B/elem) ----
#define OFF_W1F   0            //  2048 bf16  =     4096 B   conv1 B-frag table
#define OFF_W2F   6144         //  32768 bf16 =    65536 B   conv2 B-frag table
#define OFF_WBBF  71680        //  1605632 bf16 = 3211264 B  gemm_u B-frag table
#define OFF_FEATB 62265344     //  1024*12544 bf16 = 25690112 B
#define OFF_U     87955456     //  131072 f32 = 524288 B   (layout [t][b][128])
#define OFF_PART  88479744     //  28*131072 f32 = 14680064 B
#define OFF_WHF   103163904    //  8192 bf16 = 16384 B   rnn Wh B-frag table
#define OFF_WGF   103180288    //  32768 bf16 = 65536 B  rnn [ff1|ff2|ta|tb] B-frag table
#define WS_BYTES  103245824

__device__ __forceinline__ unsigned short f2bf(float v) {
    union { float f; unsigned int u; } c; c.f = v;
    unsigned int r = c.u + 0x7FFFu + ((c.u >> 16) & 1u);   // RNE
    return (unsigned short)(r >> 16);
}
__device__ __forceinline__ float bf2f(unsigned short h) {
    union { unsigned int u; float f; } c; c.u = ((unsigned int)h) << 16;
    return c.f;
}
// pack 2 f32 -> 2 bf16 in one dword, RNE, KNOWN-GOOD scalar path (no asm)
__device__ __forceinline__ unsigned int pack2bf(float lo, float hi) {
    return (unsigned int)f2bf(lo) | ((unsigned int)f2bf(hi) << 16);
}

__device__ __forceinline__ float fast_tanh(float x) {
    x = __builtin_amdgcn_fmed3f(x, -15.f, 15.f);
    float e = __expf(2.f * x);
    return (e - 1.f) * __builtin_amdgcn_rcpf(e + 1.f);
}
__device__ __forceinline__ float fast_sigmoid(float x) {
    x = __builtin_amdgcn_fmed3f(x, -30.f, 30.f);
    return __builtin_amdgcn_rcpf(1.f + __expf(-x));
}

// ---------------- merged weight-prep kernel (5-in-1) ----------------
__global__ __launch_bounds__(256) void prep_all(const float* __restrict__ w1, const float* __restrict__ w2,
                         const float* __restrict__ Wbb,
                         const float* __restrict__ Wff1, const float* __restrict__ Wff2,
                         const float* __restrict__ Wta,  const float* __restrict__ Wtb,
                         unsigned short* __restrict__ w1f, unsigned short* __restrict__ w2f,
                         unsigned short* __restrict__ wbbf,
                         unsigned short* __restrict__ whf, unsigned short* __restrict__ wgf) {
    int bid = blockIdx.x, tid = threadIdx.x;
    if (bid < 6272) {                       // Wbb(feat) -> wbbf, 1605632
        int i = bid * 256 + tid;
        int j = i & 7, lane = (i >> 3) & 63, nt = (i >> 9) & 7, kstep = i >> 12;
        int f = kstep * 32 + (lane >> 4) * 8 + j;
        int col = nt * 16 + (lane & 15);
        wbbf[i] = f2bf(Wbb[(size_t)f * 128 + col]);
    } else if (bid < 6400) {                // w2 -> w2f, 32768
        int i = (bid - 6272) * 256 + tid;
        int j = i & 7, lane = (i >> 3) & 63, kstep = (i >> 9) & 15, nt = i >> 13;
        int oc = nt * 16 + (lane & 15);
        int ic = 2 * kstep + (j >> 2);
        int ky = lane >> 4, kx = j & 3;
        w2f[i] = f2bf(w2[oc * 512 + ic * 16 + ky * 4 + kx]);
    } else if (bid < 6528) {                // gates -> wgf, 32768
        int i = (bid - 6400) * 256 + tid;
        int j = i & 7, lane = (i >> 3) & 63, nt = (i >> 9) & 15, kstep = (i >> 13) & 3;
        int k = kstep * 32 + ((lane >> 4) & 3) * 8 + j;
        int m = nt >> 2;
        int c = (nt & 3) * 16 + (lane & 15);
        const float* Wm = (m == 0) ? Wff1 : (m == 1) ? Wff2 : (m == 2) ? Wta : Wtb;
        wgf[i] = f2bf(Wm[k * 64 + c]);
    } else if (bid < 6560) {                // Wh -> whf, 8192
        int i = (bid - 6528) * 256 + tid;
        int j = i & 7, lane = (i >> 3) & 63, nt = (i >> 9) & 7, kstep = (i >> 12) & 1;
        int k = kstep * 32 + ((lane >> 4) & 3) * 8 + j;
        int col = nt * 16 + (lane & 15);
        whf[i] = f2bf(Wbb[(size_t)(FEATN + k) * 128 + col]);
    } else {                                // w1 -> w1f, 2048
        int i = (bid - 6560) * 256 + tid;
        if (i >= 2048) return;
        int j = i & 7, lane = (i >> 3) & 63, nt = (i >> 9) & 1, kstep = (i >> 10) & 1;
        int oc = nt * 16 + (lane & 15);
        int ky = (lane >> 4) & 3, kx = j & 3;
        float v;
        if (kstep == 0) { int ic = j >> 2; v = w1[oc * 48 + ic * 16 + ky * 4 + kx]; }
        else            { v = (j >> 2) == 0 ? w1[oc * 48 + 32 + ky * 4 + kx] : 0.f; }
        w1f[i] = f2bf(v);
    }
}

// ---------------- fused conv1+conv2, bf16 MFMA, h1 lives only in LDS ----------------
// 512 threads = 8 waves (2 blocks/CU at 61.7KB LDS -> 16 waves/CU for latency hiding).
// Part A (conv1): 57 mtiles over 8 waves (<=8 iters). Part B (conv2): 13 mtiles (<=2 iters).
__global__ __launch_bounds__(512) void fused_conv(const float* __restrict__ x,
                                                  const float* __restrict__ b1,
                                                  const unsigned short* __restrict__ w1f,
                                                  const float* __restrict__ b2,
                                                  const unsigned short* __restrict__ w2f,
                                                  unsigned short* __restrict__ featb) {
    __shared__ unsigned short h1s[32 * 2 * PLANEP];   // 61696 B
    int img = blockIdx.x;
    int tid = threadIdx.x;
    int lane = tid & 63, wid = tid >> 6;               // wid 0..7
    int rowl = lane & 15, g = lane >> 4;
    const float* xg = x + (size_t)img * 11532;

    // ---- Part A: conv1 -> h1s ----
    {
        short8 bfr[2][2];
        #pragma unroll
        for (int ks = 0; ks < 2; ++ks)
            #pragma unroll
            for (int nt = 0; nt < 2; ++nt)
                bfr[ks][nt] = *(const short8*)(w1f + (((ks * 2 + nt) * 64 + lane) << 3));
        float bias0 = b1[rowl], bias1 = b1[16 + rowl];

        #pragma unroll
        for (int i = 0; i < 8; ++i) {
            int mtile = wid + 8 * i;
            if (mtile >= 57) break;
            int m = mtile * 16 + rowl; if (m > 899) m = 899;
            int oy = m / 30, ox = m - oy * 30;
            int y = 2 * oy + g, x0 = 2 * ox;
            const float* xb = xg + y * 62 + x0;
            union { unsigned int u[4]; short8 s; } af0, af1;
            #pragma unroll
            for (int c = 0; c < 2; ++c) {
                float2 p0 = *(const float2*)(xb + c * 3844);
                float2 p1 = *(const float2*)(xb + c * 3844 + 2);
                af0.u[c * 2]     = pack2bf(p0.x, p0.y);
                af0.u[c * 2 + 1] = pack2bf(p1.x, p1.y);
            }
            {
                float2 q0 = *(const float2*)(xb + 7688);
                float2 q1 = *(const float2*)(xb + 7690);
                af1.u[0] = pack2bf(q0.x, q0.y);
                af1.u[1] = pack2bf(q1.x, q1.y);
                af1.u[2] = 0; af1.u[3] = 0;
            }
            f32x4 acc0 = (f32x4){0.f, 0.f, 0.f, 0.f};
            f32x4 acc1 = (f32x4){0.f, 0.f, 0.f, 0.f};
            acc0 = __builtin_amdgcn_mfma_f32_16x16x32_bf16(af0.s, bfr[0][0], acc0, 0, 0, 0);
            acc0 = __builtin_amdgcn_mfma_f32_16x16x32_bf16(af1.s, bfr[1][0], acc0, 0, 0, 0);
            acc1 = __builtin_amdgcn_mfma_f32_16x16x32_bf16(af0.s, bfr[0][1], acc1, 0, 0, 0);
            acc1 = __builtin_amdgcn_mfma_f32_16x16x32_bf16(af1.s, bfr[1][1], acc1, 0, 0, 0);
            // epilogue: bias+relu+bf16 -> h1s[oc][oy][ox]
            int sp0 = mtile * 16 + g * 4;
            int oy0 = sp0 / 30, ox0 = sp0 - oy0 * 30;
            #pragma unroll
            for (int nt = 0; nt < 2; ++nt) {
                f32x4 a = nt ? acc1 : acc0;
                int oc = nt * 16 + rowl;
                float bias = nt ? bias1 : bias0;
                int pbase = oc * (2 * PLANEP);
                #pragma unroll
                for (int r = 0; r < 4; ++r) {
                    if (sp0 + r > 899) break;
                    int oxr = ox0 + r, oyr = oy0;
                    if (oxr >= 30) { oxr -= 30; ++oyr; }
                    h1s[pbase + oyr * 32 + oxr] = f2bf(fmaxf(a[r] + bias, 0.f));
                }
            }
        }
    }
    __syncthreads();

    // ---- Part B: conv2 -> featb ----
    f32x4 acc[2][4];
    #pragma unroll
    for (int i = 0; i < 2; ++i)
        #pragma unroll
        for (int nt = 0; nt < 4; ++nt) acc[i][nt] = (f32x4){0.f, 0.f, 0.f, 0.f};

    int dofs[2];
    #pragma unroll
    for (int i = 0; i < 2; ++i) {
        int mtile = wid + 8 * i;
        int m = mtile * 16 + rowl; if (m > 195) m = 195;
        int oy = m / 14, ox = m - oy * 14;
        int y = 2 * oy + g, x0 = 2 * ox;
        dofs[i] = y * 16 + (x0 >> 1);
    }
    const unsigned int* lds32 = (const unsigned int*)h1s;

    #pragma unroll 4
    for (int kstep = 0; kstep < 16; ++kstep) {
        short8 bfr[4];
        #pragma unroll
        for (int nt = 0; nt < 4; ++nt)
            bfr[nt] = *(const short8*)(w2f + (((nt * 16 + kstep) * 64 + lane) << 3));
        int icb = kstep * 2 * PLANEP;
        #pragma unroll
        for (int i = 0; i < 2; ++i) {
            int mtile = wid + 8 * i;
            if (mtile < 13) {
                int dof = icb + dofs[i];
                union { unsigned int u[4]; short8 s; } af;
                af.u[0] = lds32[dof];
                af.u[1] = lds32[dof + 1];
                af.u[2] = lds32[dof + PLANEP];
                af.u[3] = lds32[dof + PLANEP + 1];
                #pragma unroll
                for (int nt = 0; nt < 4; ++nt)
                    acc[i][nt] = __builtin_amdgcn_mfma_f32_16x16x32_bf16(af.s, bfr[nt], acc[i][nt], 0, 0, 0);
            }
        }
    }
    #pragma unroll
    for (int i = 0; i < 2; ++i) {
        int mtile = wid + 8 * i;
        if (mtile >= 13) continue;
        int sp0 = mtile * 16 + g * 4;
        #pragma unroll
        for (int nt = 0; nt < 4; ++nt) {
            int oc = nt * 16 + rowl;
            float bias = b2[oc];
            unsigned short pk[4];
            #pragma unroll
            for (int r = 0; r < 4; ++r)
                pk[r] = f2bf(fmaxf(acc[i][nt][r] + bias, 0.f));
            unsigned short* dstp = featb + (size_t)img * 12544 + oc * 196 + sp0;
            if (sp0 + 3 < 196) {
                *(uint2*)dstp = *(uint2*)pk;
            } else {
                #pragma unroll
                for (int r = 0; r < 4; ++r) if (sp0 + r < 196) dstp[r] = pk[r];
            }
        }
    }
}

// ---------------- u = feat @ W_in : bf16 MFMA, split-K=28 ----------------
__global__ __launch_bounds__(256) void gemm_u_mfma(const unsigned short* __restrict__ featb,
                                                   const unsigned short* __restrict__ Wbbf,
                                                   float* __restrict__ part) {
    int tid = threadIdx.x, lane = tid & 63, wid = tid >> 6;
    int rowl = lane & 15, g = lane >> 4;
    int m0 = blockIdx.x * 64 + wid * 16;
    int ks0 = blockIdx.y * 14;
    f32x4 acc[8];
    #pragma unroll
    for (int nt = 0; nt < 8; ++nt) acc[nt] = (f32x4){0.f, 0.f, 0.f, 0.f};
    const unsigned short* arow = featb + (size_t)(m0 + rowl) * FEATN + g * 8;
    #pragma unroll 2
    for (int kk = 0; kk < 14; ++kk) {
        int kstep = ks0 + kk;
        short8 afr = *(const short8*)(arow + kstep * 32);
        #pragma unroll
        for (int nt = 0; nt < 8; ++nt) {
            short8 bfr = *(const short8*)(Wbbf + ((((size_t)kstep * 8 + nt) * 64 + lane) << 3));
            acc[nt] = __builtin_amdgcn_mfma_f32_16x16x32_bf16(afr, bfr, acc[nt], 0, 0, 0);
        }
    }
    float* pg = part + (size_t)blockIdx.y * 131072;
    #pragma unroll
    for (int nt = 0; nt < 8; ++nt)
        #pragma unroll
        for (int r = 0; r < 4; ++r)
            pg[(m0 + g * 4 + r) * 128 + nt * 16 + rowl] = acc[nt][r];
}

// reduce into u laid out [t][b][128]
__global__ void reduce_u(const float* __restrict__ part, const float* __restrict__ bbb,
                         float* __restrict__ u) {
    int o = blockIdx.x * 256 + threadIdx.x;   // 131072 total
    int c = o & 127, b = (o >> 7) & 15, t = o >> 11;
    int m = b * 64 + t;
    float s = bbb[c];
    #pragma unroll
    for (int ks = 0; ks < 28; ++ks) s += part[(size_t)ks * 131072 + m * 128 + c];
    u[o] = s;
}

// ---------------- liquid RNN scan + fused head: 1 block, 4 waves, single-bf16 state ----------------
__global__ __launch_bounds__(256, 1) void rnn_mfma(const float* __restrict__ u,
                                                   const unsigned short* __restrict__ whf,
                                                   const unsigned short* __restrict__ wgf,
                                                   const float* __restrict__ bff1,
                                                   const float* __restrict__ bff2,
                                                   const float* __restrict__ bta,
                                                   const float* __restrict__ btb,
                                                   const float* __restrict__ Wout,
                                                   const float* __restrict__ bout,
                                                   float* __restrict__ out) {
    __shared__ unsigned short hidA[16 * 64];    // [row][k0..63]
    __shared__ unsigned short zA[16 * 128];     // [row][k0..127]  (reused as f32 hid for head)
    int tid = threadIdx.x, lane = tid & 63, w = tid >> 6;
    int rowl = lane & 15, g = lane >> 4;

    for (int idx = tid; idx < 1024; idx += 256) hidA[idx] = 0;

    // B-fragments -> registers (once)
    short8 wh_r[2][2];   // [kstep][ntl], nt_abs = 2w + ntl
    #pragma unroll
    for (int ks = 0; ks < 2; ++ks)
        #pragma unroll
        for (int ntl = 0; ntl < 2; ++ntl)
            wh_r[ks][ntl] = *(const short8*)(whf + (((ks * 8 + 2 * w + ntl) * 64 + lane) << 3));
    short8 wg_r[4][4];   // [m][kstep], nt_abs = 4m + w
    #pragma unroll
    for (int m = 0; m < 4; ++m)
        #pragma unroll
        for (int ks = 0; ks < 4; ++ks)
            wg_r[m][ks] = *(const short8*)(wgf + (((ks * 16 + 4 * m + w) * 64 + lane) << 3));

    int cc = w * 16 + rowl;                   // this lane's phase-2 column
    float bias1 = bff1[cc], bias2 = bff2[cc], biast = bta[cc] + btb[cc];

    // u prefetch (t=0)
    float upf[8];
    #pragma unroll
    for (int i = 0; i < 8; ++i) {
        int ntl = i >> 2, r = i & 3;
        upf[i] = u[(g * 4 + r) * 128 + (2 * w + ntl) * 16 + rowl];
    }
    __syncthreads();

    float hidv[4];
    #pragma unroll 1
    for (int t = 0; t < 64; ++t) {
        // ---- Phase 1: z = lecun_tanh(u_t + hid @ Wh) ----
        short8 ah[2];
        #pragma unroll
        for (int ks = 0; ks < 2; ++ks) {
            int byte = (rowl * 128 + ks * 64 + g * 16) ^ ((rowl & 7) << 4);
            ah[ks] = *(const short8*)((const char*)hidA + byte);
        }
        f32x4 zacc[2];
        #pragma unroll
        for (int ntl = 0; ntl < 2; ++ntl) {
            zacc[ntl] = (f32x4){upf[ntl * 4 + 0], upf[ntl * 4 + 1], upf[ntl * 4 + 2], upf[ntl * 4 + 3]};
            #pragma unroll
            for (int ks = 0; ks < 2; ++ks)
                zacc[ntl] = __builtin_amdgcn_mfma_f32_16x16x32_bf16(ah[ks], wh_r[ks][ntl], zacc[ntl], 0, 0, 0);
        }
        // prefetch u for t+1 (overlaps rest of step)
        if (t < 63) {
            #pragma unroll
            for (int i = 0; i < 8; ++i) {
                int ntl = i >> 2, r = i & 3;
                upf[i] = u[(t + 1) * 2048 + (g * 4 + r) * 128 + (2 * w + ntl) * 16 + rowl];
            }
        }
        // tanh + write z (bf16) to LDS
        #pragma unroll
        for (int ntl = 0; ntl < 2; ++ntl)
            #pragma unroll
            for (int r = 0; r < 4; ++r) {
                float zv = 1.7159f * fast_tanh(0.666f * zacc[ntl][r]);
                int row = g * 4 + r, c = w * 32 + ntl * 16 + rowl;
                int byte = (row * 256 + c * 2) ^ ((row & 7) << 4);
                *(unsigned short*)((char*)zA + byte) = f2bf(zv);
            }
        __syncthreads();
        // ---- Phase 2: [ff1|ff2|ta|tb] = z @ Wg ----
        short8 zfr[4];
        #pragma unroll
        for (int ks = 0; ks < 4; ++ks) {
            int byte = (rowl * 256 + ks * 64 + g * 16) ^ ((rowl & 7) << 4);
            zfr[ks] = *(const short8*)((const char*)zA + byte);
        }
        f32x4 facc[4];
        facc[0] = (f32x4){bias1, bias1, bias1, bias1};
        facc[1] = (f32x4){bias2, bias2, bias2, bias2};
        facc[2] = (f32x4){biast, biast, biast, biast};
        facc[3] = (f32x4){0.f, 0.f, 0.f, 0.f};
        #pragma unroll
        for (int m = 0; m < 4; ++m)
            #pragma unroll
            for (int ks = 0; ks < 4; ++ks)
                facc[m] = __builtin_amdgcn_mfma_f32_16x16x32_bf16(zfr[ks], wg_r[m][ks], facc[m], 0, 0, 0);
        // activations + hid write (bf16)
        #pragma unroll
        for (int r = 0; r < 4; ++r) {
            float ff1 = fast_tanh(facc[0][r]);
            float ff2 = fast_tanh(facc[1][r]);
            float tt  = fast_sigmoid(facc[2][r] + facc[3][r]);
            float hv  = ff1 * (1.f - tt) + tt * ff2;
            hidv[r] = hv;
            int row = g * 4 + r;
            int byte = (row * 128 + cc * 2) ^ ((row & 7) << 4);
            *(unsigned short*)((char*)hidA + byte) = f2bf(hv);
        }
        __syncthreads();
    }

    // ---- fused head: out[b][a] = hid[b] . Wout[:,a] + bout[a] ----
    float* hf = (float*)zA;                    // 16*64 f32 = 4096 B (zA is 4096 B)
    #pragma unroll
    for (int r = 0; r < 4; ++r) hf[(g * 4 + r) * 64 + cc] = hidv[r];
    __syncthreads();
    if (tid < 128) {
        int b = tid >> 3, a = tid & 7;
        float s = bout[a];
        #pragma unroll
        for (int j = 0; j < 64; ++j) s += hf[b * 64 + j] * Wout[j * 8 + a];
        out[tid] = s;
    }
}

extern "C" void kernel_launch(void* const* d_in, const int* in_sizes, int n_in,
                              void* d_out, int out_size, void* d_ws, size_t ws_size,
                              hipStream_t stream) {
    const float* x    = (const float*)d_in[0];
    const float* w1   = (const float*)d_in[1];
    const float* b1   = (const float*)d_in[2];
    const float* w2   = (const float*)d_in[3];
    const float* b2   = (const float*)d_in[4];
    const float* Wbb  = (const float*)d_in[5];
    const float* bbb  = (const float*)d_in[6];
    const float* Wff1 = (const float*)d_in[7];
    const float* bff1 = (const float*)d_in[8];
    const float* Wff2 = (const float*)d_in[9];
    const float* bff2 = (const float*)d_in[10];
    const float* Wta  = (const float*)d_in[11];
    const float* bta  = (const float*)d_in[12];
    const float* Wtb  = (const float*)d_in[13];
    const float* btb  = (const float*)d_in[14];
    const float* Wout = (const float*)d_in[15];
    const float* bout = (const float*)d_in[16];

    if (ws_size < (size_t)WS_BYTES) return;

    char* wsb = (char*)d_ws;
    unsigned short* w1f   = (unsigned short*)(wsb + OFF_W1F);
    unsigned short* w2f   = (unsigned short*)(wsb + OFF_W2F);
    unsigned short* wbbf  = (unsigned short*)(wsb + OFF_WBBF);
    unsigned short* featb = (unsigned short*)(wsb + OFF_FEATB);
    float*          u     = (float*)(wsb + OFF_U);
    float*          part  = (float*)(wsb + OFF_PART);
    unsigned short* whf   = (unsigned short*)(wsb + OFF_WHF);
    unsigned short* wgf   = (unsigned short*)(wsb + OFF_WGF);

    prep_all<<<6568, 256, 0, stream>>>(w1, w2, Wbb, Wff1, Wff2, Wta, Wtb,
                                       w1f, w2f, wbbf, whf, wgf);
    fused_conv<<<1024, 512, 0, stream>>>(x, b1, w1f, b2, w2f, featb);
    gemm_u_mfma<<<dim3(16, 28), 256, 0, stream>>>(featb, wbbf, part);
    reduce_u<<<512, 256, 0, stream>>>(part, bbb, u);
    rnn_mfma<<<1, 256, 0, stream>>>(u, whf, wgf, bff1, bff2, bta, btb, Wout, bout, (float*)d_out);
}